// Round 2
// baseline (216.100 us; speedup 1.0000x reference)
//
#include <hip/hip_runtime.h>
#include <hip/hip_bf16.h>

#define BSZ 4
#define CC 64
#define NN 4096
#define CN (CC*NN)        // 262144
#define BCN (BSZ*CN)      // 1048576

typedef __attribute__((ext_vector_type(4))) float    f4v;
typedef __attribute__((ext_vector_type(4))) int      i4v;
typedef __attribute__((ext_vector_type(2))) int      i2v;
typedef __attribute__((ext_vector_type(8))) short    s8v;

// DPP cross-lane (VALU pipe): quad_perm within quads
#define DPP_F(x_, ctrl_) __builtin_bit_cast(float, \
    __builtin_amdgcn_update_dpp(0, __builtin_bit_cast(int, (float)(x_)), (ctrl_), 0xf, 0xf, true))
#define QP_X1 0xB1   // quad_perm [1,0,3,2]

__device__ __forceinline__ unsigned pack_bf16(float lo, float hi) {
    unsigned l = __builtin_bit_cast(unsigned, lo);
    unsigned h = __builtin_bit_cast(unsigned, hi);
    return (h & 0xFFFF0000u) | (l >> 16);
}
// single v_cvt_pk_bf16_f32 (RNE)
__device__ __forceinline__ unsigned pack2(float lo, float hi) {
    float2 f2; f2.x = lo; f2.y = hi;
    __hip_bfloat162 h = __float22bfloat162_rn(f2);
    unsigned u;
    __builtin_memcpy(&u, &h, 4);
    return u;
}

// Soft grid barrier: monotonic counter (zeroed by memset in the capture each
// replay). All 256 blocks are co-resident (LDS 36KB, ~100 VGPR -> >=2
// blocks/CU capacity; grid == 256 <= capacity), so spin cannot deadlock.
__device__ __forceinline__ void gsync(unsigned* ctr, unsigned target) {
    __syncthreads();
    if (threadIdx.x == 0) {
        __threadfence();                                  // release prior writes
        atomicAdd(ctr, 1u);                               // device-scope
        while (__hip_atomic_load(ctr, __ATOMIC_ACQUIRE,
                                 __HIP_MEMORY_SCOPE_AGENT) < target)
            __builtin_amdgcn_s_sleep(2);
        __threadfence();                                  // acquire for block
    }
    __syncthreads();
}

// ---------------------------------------------------------------------------
// Kernel A: gram -> gred -> weff -> qkv, one launch, 3 soft grid barriers.
// grid 256 x 256. Shared smem is unioned across phases (max 9216 floats).
__global__ __launch_bounds__(256) void fused_a(
        const float* __restrict__ cnn, const float* __restrict__ vit,
        const float* __restrict__ Wq,  const float* __restrict__ Wk,
        const float* __restrict__ Wv,
        const float* __restrict__ gcnn, const float* __restrict__ gvit,
        const float* __restrict__ bq,  const float* __restrict__ bk,
        const float* __restrict__ bv,
        float* __restrict__ part, float* __restrict__ G,
        ushort* __restrict__ WeffB,
        ushort* __restrict__ qb, ushort* __restrict__ kb,
        ushort* __restrict__ vT, unsigned* __restrict__ ctr) {
    __shared__ __align__(16) float smem[9216];            // 36 KB
    int t = threadIdx.x;
    int blk = blockIdx.x;

    // ---- phase 1: gram partials (identical mapping to old gram_k) ----
    {
        float* sXT = smem;                                // [n][c], pitch 68
        int ch = blk & 31, b = (blk >> 5) & 3, i2 = blk >> 7;
        const float* X = (i2 ? vit : cnn) + b * CN;
        int n0 = ch * 128;
#pragma unroll
        for (int j = 0; j < 8; j++) {
            int idx = t + j * 256;
            int c = idx >> 5, n4 = idx & 31;
            f4v val = *(const f4v*)&X[c * NN + n0 + n4 * 4];
            int base = (n4 * 4) * 68 + c;
            sXT[base]       = val[0];
            sXT[base + 68]  = val[1];
            sXT[base + 136] = val[2];
            sXT[base + 204] = val[3];
        }
        __syncthreads();
        int tc = (t & 15) * 4, td = (t >> 4) * 4;
        f4v acc[4];
#pragma unroll
        for (int i = 0; i < 4; i++) acc[i] = (f4v){0.f, 0.f, 0.f, 0.f};
#pragma unroll 4
        for (int k = 0; k < 128; k++) {
            f4v a  = *(const f4v*)&sXT[k * 68 + tc];
            f4v bb = *(const f4v*)&sXT[k * 68 + td];
#pragma unroll
            for (int i = 0; i < 4; i++) acc[i] += a[i] * bb;
        }
        float* dst = part + ch * 32768 + (i2 * 4 + b) * 4096;
#pragma unroll
        for (int i = 0; i < 4; i++) *(f4v*)&dst[(tc + i) * 64 + td] = acc[i];
    }
    gsync(ctr, 256);

    // ---- phase 2: reduce 32 partials + channel softmax (2 rows/block) ----
    {
        int w = t >> 6, d = t & 63;
        int row = blk * 2 + (w & 1), hf = w >> 1;
        float s = 0.f;
#pragma unroll
        for (int ch = hf * 16; ch < hf * 16 + 16; ch++)
            s += part[ch * 32768 + row * 64 + d];
        smem[w * 64 + d] = s;
        __syncthreads();
        if (w < 2) {
            int r = blk * 2 + w;
            float sv = smem[w * 64 + d] + smem[(w + 2) * 64 + d];
            float mn = sv;
#pragma unroll
            for (int off = 1; off < 64; off <<= 1) mn = fminf(mn, __shfl_xor(mn, off));
            float e = __expf(mn - sv);
            float sm2 = e;
#pragma unroll
            for (int off = 1; off < 64; off <<= 1) sm2 += __shfl_xor(sm2, off);
            G[r * 64 + d] = e / sm2;
        }
    }
    gsync(ctr, 512);

    // ---- phase 3: effective weights + MFMA A-frag pack (blocks 0..19) ----
    if (blk < 20) {
        float* sA = smem;                                 // 8192 f
        float* sWt = smem + 8192;                         // 1024 f
        int b = blk / 5, tile = blk % 5;
        for (int i = t; i < 4096; i += 256) {
            sA[i]        = G[b * 4096 + i];
            sA[4096 + i] = G[(4 + b) * 4096 + i];
        }
        __syncthreads();
        float gc = *gcnn, gv = *gvit;
#pragma unroll
        for (int k = 0; k < 4; k++) {
            int idx = k * 256 + t;
            int r = idx >> 6, c = idx & 63;
            const float* Wrow; const float* A; float g;
            if (tile == 0) {
                if (r < 8) { Wrow = Wq + r * 64;       A = sA;        g = gc; }
                else       { Wrow = Wk + (r - 8) * 64; A = sA + 4096; g = gv; }
            } else         { Wrow = Wv + ((tile - 1) * 16 + r) * 64; A = sA + 4096; g = gv; }
            float s = 0.f;
#pragma unroll 8
            for (int d = 0; d < 64; d++) s += Wrow[d] * A[d * 64 + c];
            sWt[idx] = g * s + Wrow[c];
        }
        __syncthreads();
        if (t < 128) {
            int frag = t >> 6, lane = t & 63, m = lane & 15, q4 = lane >> 4;
            i4v o;
#pragma unroll
            for (int p = 0; p < 4; p++) {
                int c0 = frag * 32 + q4 * 8 + 2 * p;
                o[p] = (int)pack_bf16(sWt[m * 64 + c0], sWt[m * 64 + c0 + 1]);
            }
            *(i4v*)&WeffB[(size_t)(b * 10 + tile * 2 + frag) * 512 + lane * 8] = o;
        }
    }
    gsync(ctr, 768);

    // ---- phase 4: MFMA QKV projections (identical to old qkv_k) ----
    {
        int b = blk >> 6, n0 = (blk & 63) * 64;
        int w = t >> 6, lane = t & 63, c15 = lane & 15, q4 = lane >> 4;
        int n = n0 + w * 16 + c15;
        const float LOG2E = 1.44269504f;

        s8v A[10];
        const ushort* WB = WeffB + (size_t)b * 5120 + lane * 8;
#pragma unroll
        for (int i = 0; i < 10; i++)
            A[i] = __builtin_bit_cast(s8v, *(const i4v*)(WB + (size_t)i * 512));

        s8v Bc[2], Bv[2];
#pragma unroll
        for (int f = 0; f < 2; f++) {
            i4v pc, pv;
#pragma unroll
            for (int p = 0; p < 4; p++) {
                int c0 = f * 32 + q4 * 8 + p * 2;
                size_t a0 = (size_t)b * CN + (size_t)c0 * NN + n;
                pc[p] = (int)pack_bf16(cnn[a0], cnn[a0 + NN]);
                pv[p] = (int)pack_bf16(vit[a0], vit[a0 + NN]);
            }
            Bc[f] = __builtin_bit_cast(s8v, pc);
            Bv[f] = __builtin_bit_cast(s8v, pv);
        }

        f4v acc = *(const f4v*)(bq + (q4 & 1) * 4);
        acc = __builtin_amdgcn_mfma_f32_16x16x32_bf16(A[0], Bc[0], acc, 0, 0, 0);
        acc = __builtin_amdgcn_mfma_f32_16x16x32_bf16(A[1], Bc[1], acc, 0, 0, 0);
        if (q4 < 2) {
            unsigned d0 = pack_bf16(acc[0] * LOG2E, acc[1] * LOG2E);
            unsigned d1 = pack_bf16(acc[2] * LOG2E, acc[3] * LOG2E);
            unsigned long long v = ((unsigned long long)d1 << 32) | d0;
            *(unsigned long long*)&qb[(size_t)(b * NN + n) * 8 + q4 * 4] = v;
        }
        acc = *(const f4v*)(bk + (q4 & 1) * 4);
        acc = __builtin_amdgcn_mfma_f32_16x16x32_bf16(A[0], Bv[0], acc, 0, 0, 0);
        acc = __builtin_amdgcn_mfma_f32_16x16x32_bf16(A[1], Bv[1], acc, 0, 0, 0);
        if (q4 >= 2) {
            unsigned d0 = pack_bf16(acc[0], acc[1]), d1 = pack_bf16(acc[2], acc[3]);
            unsigned long long v = ((unsigned long long)d1 << 32) | d0;
            *(unsigned long long*)&kb[(size_t)(b * NN + n) * 8 + (q4 - 2) * 4] = v;
        }
#pragma unroll
        for (int tile = 1; tile < 5; tile++) {
            acc = *(const f4v*)(bv + (tile - 1) * 16 + q4 * 4);
            acc = __builtin_amdgcn_mfma_f32_16x16x32_bf16(A[tile * 2],     Bv[0], acc, 0, 0, 0);
            acc = __builtin_amdgcn_mfma_f32_16x16x32_bf16(A[tile * 2 + 1], Bv[1], acc, 0, 0, 0);
#pragma unroll
            for (int r = 0; r < 4; r++) {
                float other = DPP_F(acc[r], QP_X1);
                unsigned pkd = (lane & 1) ? pack_bf16(other, acc[r])
                                          : pack_bf16(acc[r], other);
                if (!(lane & 1)) {
                    int row = (tile - 1) * 16 + q4 * 4 + r;
                    *(unsigned*)&vT[(size_t)(b * 64 + row) * NN + n] = pkd;
                }
            }
        }
    }
}

// ---------------------------------------------------------------------------
// Kernel B: flash + combine fused, NO global split-K. grid 256 = (b:4, qc:64
// of 64 q), 512 threads = 8 waves. Wave pair (wq, half): waves 0-3 take k
// 0..2047, waves 4-7 take k 2048..4095 for the same 16-q groups; O/L combined
// through LDS at the end; epilogue writes out = gamma*O/L + cnn directly.
// V double-buffered in LDS per half (one barrier per kt), pi-permuted so each
// lane's PV A-frag is one contiguous ds_read_b128.
__global__ __launch_bounds__(512, 2) void flashc_k(
        const ushort* __restrict__ qb, const ushort* __restrict__ kb,
        const ushort* __restrict__ vT, const float* __restrict__ cnn,
        const float* __restrict__ gamma, float* __restrict__ out) {
    __shared__ __align__(16) ushort Vlds[4 * 4608];       // [tile][dbuf][64][72]
    __shared__ float sO[4 * 16 * 64];                     // pair combine
    __shared__ float sL[4 * 64];

    int t = threadIdx.x;
    int lane = t & 63, w = t >> 6;                        // w 0..7
    int c15 = lane & 15, q4 = lane >> 4;
    int blk = blockIdx.x;
    int b = blk >> 6, q0 = (blk & 63) * 64;
    int wq = w & 3, half = w >> 2;

    // Q frag (B-operand); only q4==0 lanes carry real features (C8=8)
    i4v qa = (i4v){0, 0, 0, 0};
    if (q4 == 0)
        qa = *(const i4v*)(qb + (size_t)(b * NN + q0 + wq * 16 + c15) * 8);
    s8v qB = __builtin_bit_cast(s8v, qa);

    f4v accO[4];
#pragma unroll
    for (int nt = 0; nt < 4; nt++) accO[nt] = (f4v){0.f, 0.f, 0.f, 0.f};
    float lacc = 0.f;

    const ushort* kbb = kb + (size_t)b * NN * 8 + (size_t)c15 * 8;
    int kbase = half * 2048;

    // staging: 512 threads cover BOTH halves' 8KB tiles (tile = t>>8)
    int stile = t >> 8;
    int sr = (t >> 2) & 63, schk = t & 3;
    const ushort* vsrc = vT + (size_t)(b * 64 + sr) * NN + stile * 2048 + schk * 16;
    int vdstoff = sr * 72 + 32 * (schk >> 1) + 4 * (schk & 1);
    int vreadoff = c15 * 72 + 8 * q4;

    // preload kt0
    i4v bk_cur[4];
#pragma unroll
    for (int nt = 0; nt < 4; nt++)
        bk_cur[nt] = *(const i4v*)(kbb + (size_t)(kbase + nt * 16) * 8);
    i4v v0 = *(const i4v*)(vsrc);
    i4v v1 = *(const i4v*)(vsrc + 8);

#pragma unroll 2
    for (int kt = 0; kt < 32; kt++) {
        ushort* vd = Vlds + (stile * 2 + (kt & 1)) * 4608 + vdstoff;
        *(i2v*)(vd + 0)  = (i2v){v0[0], v0[1]};
        *(i2v*)(vd + 8)  = (i2v){v0[2], v0[3]};
        *(i2v*)(vd + 16) = (i2v){v1[0], v1[1]};
        *(i2v*)(vd + 24) = (i2v){v1[2], v1[3]};
        __syncthreads();

        const ushort* vb = Vlds + (half * 2 + (kt & 1)) * 4608 + vreadoff;
        i4v vA[2][4];
#pragma unroll
        for (int F = 0; F < 2; F++)
#pragma unroll
            for (int nt = 0; nt < 4; nt++)
                vA[F][nt] = *(const i4v*)(vb + nt * 16 * 72 + 32 * F);

        i4v bk_nxt[4];
        if (kt < 31) {
            v0 = *(const i4v*)(vsrc + (kt + 1) * 64);
            v1 = *(const i4v*)(vsrc + (kt + 1) * 64 + 8);
#pragma unroll
            for (int nt = 0; nt < 4; nt++)
                bk_nxt[nt] = *(const i4v*)(kbb +
                    (size_t)(kbase + (kt + 1) * 64 + nt * 16) * 8);
        }

        f4v z = (f4v){0.f, 0.f, 0.f, 0.f};
        f4v S[4];
#pragma unroll
        for (int nt = 0; nt < 4; nt++)
            S[nt] = __builtin_amdgcn_mfma_f32_16x16x32_bf16(
                __builtin_bit_cast(s8v, bk_cur[nt]), qB, z, 0, 0, 0);

        f4v p[4];
        float ps = 0.f;
#pragma unroll
        for (int nt = 0; nt < 4; nt++)
#pragma unroll
            for (int rr = 0; rr < 4; rr++) {
                p[nt][rr] = __builtin_amdgcn_exp2f(S[nt][rr]);
                ps += p[nt][rr];
            }
        lacc += ps;
        s8v Bp[2];
#pragma unroll
        for (int F = 0; F < 2; F++) {
            i4v bp;
            bp[0] = (int)pack2(p[2 * F][0],     p[2 * F][1]);
            bp[1] = (int)pack2(p[2 * F][2],     p[2 * F][3]);
            bp[2] = (int)pack2(p[2 * F + 1][0], p[2 * F + 1][1]);
            bp[3] = (int)pack2(p[2 * F + 1][2], p[2 * F + 1][3]);
            Bp[F] = __builtin_bit_cast(s8v, bp);
        }

        __builtin_amdgcn_s_setprio(1);
#pragma unroll
        for (int F = 0; F < 2; F++)
#pragma unroll
            for (int nt = 0; nt < 4; nt++)
                accO[nt] = __builtin_amdgcn_mfma_f32_16x16x32_bf16(
                    __builtin_bit_cast(s8v, vA[F][nt]), Bp[F], accO[nt], 0, 0, 0);
        __builtin_amdgcn_s_setprio(0);

        if (kt < 31) {
#pragma unroll
            for (int nt = 0; nt < 4; nt++) bk_cur[nt] = bk_nxt[nt];
        }
    }

    // L over this half's 64 k-rows per q-col (lanes sharing c15)
    lacc += __shfl_xor(lacc, 16);
    lacc += __shfl_xor(lacc, 32);

    // cross-half combine through LDS
    if (half == 1) {
#pragma unroll
        for (int nt = 0; nt < 4; nt++)
#pragma unroll
            for (int rr = 0; rr < 4; rr++)
                sO[(wq * 16 + nt * 4 + rr) * 64 + lane] = accO[nt][rr];
        sL[wq * 64 + lane] = lacc;
    }
    __syncthreads();
    if (half == 0) {
        lacc += sL[wq * 64 + lane];
        float rv = *gamma / lacc;
#pragma unroll
        for (int nt = 0; nt < 4; nt++)
#pragma unroll
            for (int rr = 0; rr < 4; rr++) {
                float o = accO[nt][rr] + sO[(wq * 16 + nt * 4 + rr) * 64 + lane];
                int c = nt * 16 + q4 * 4 + rr;
                size_t gi = (size_t)(b * 64 + c) * NN + q0 + wq * 16 + c15;
                out[gi] = o * rv + cnn[gi];
            }
    }
}

// ---------------------------------------------------------------------------
extern "C" void kernel_launch(void* const* d_in, const int* in_sizes, int n_in,
                              void* d_out, int out_size, void* d_ws, size_t ws_size,
                              hipStream_t stream) {
    const float* cnn  = (const float*)d_in[0];
    const float* vit  = (const float*)d_in[1];
    const float* Wq   = (const float*)d_in[2];
    const float* bq   = (const float*)d_in[3];
    const float* Wk   = (const float*)d_in[4];
    const float* bk   = (const float*)d_in[5];
    const float* Wv   = (const float*)d_in[6];
    const float* bv   = (const float*)d_in[7];
    const float* gam  = (const float*)d_in[8];
    const float* gcnn = (const float*)d_in[9];
    const float* gvit = (const float*)d_in[10];
    float* out = (float*)d_out;

    float* ws = (float*)d_ws;
    float*    part  = ws;                        // 1,048,576 f (4 MB)
    float*    G     = ws + 1048576;              // 32,768 f
    ushort*   WeffB = (ushort*)(ws + 1081344);   // 20,480 bf16
    ushort*   qb    = (ushort*)(ws + 1091584);   // 131,072 bf16
    ushort*   kb    = (ushort*)(ws + 1157120);   // 131,072 bf16
    ushort*   vT    = (ushort*)(ws + 1222656);   // 1,048,576 bf16
    unsigned* ctr   = (unsigned*)(ws + 1746944); // soft-barrier counter

    hipMemsetAsync(ctr, 0, 4, stream);           // re-zero every replay
    fused_a<<<256, 256, 0, stream>>>(cnn, vit, Wq, Wk, Wv, gcnn, gvit,
                                     bq, bk, bv, part, G, WeffB, qb, kb, vT, ctr);
    flashc_k<<<256, 512, 0, stream>>>(qb, kb, vT, cnn, gam, out);
}

// Round 3
// 125.135 us; speedup vs baseline: 1.7269x; 1.7269x over previous
//
#include <hip/hip_runtime.h>
#include <hip/hip_bf16.h>

#define BSZ 4
#define CC 64
#define NN 4096
#define CN (CC*NN)        // 262144
#define BCN (BSZ*CN)      // 1048576

typedef __attribute__((ext_vector_type(4))) float    f4v;
typedef __attribute__((ext_vector_type(4))) int      i4v;
typedef __attribute__((ext_vector_type(2))) int      i2v;
typedef __attribute__((ext_vector_type(8))) short    s8v;

__device__ __forceinline__ unsigned pack_bf16(float lo, float hi) {
    unsigned l = __builtin_bit_cast(unsigned, lo);
    unsigned h = __builtin_bit_cast(unsigned, hi);
    return (h & 0xFFFF0000u) | (l >> 16);
}
// single v_cvt_pk_bf16_f32 (RNE)
__device__ __forceinline__ unsigned pack2(float lo, float hi) {
    float2 f2; f2.x = lo; f2.y = hi;
    __hip_bfloat162 h = __float22bfloat162_rn(f2);
    unsigned u;
    __builtin_memcpy(&u, &h, 4);
    return u;
}

// ---------------------------------------------------------------------------
// K1: gram partials, 128-wide n-chunks. grid 256 = (i2:2, b:4, chunk:32).
// X staged transposed in LDS, 4x4 register tile per thread; k-loop unroll 4.
__global__ __launch_bounds__(256) void gram_k(const float* __restrict__ cnn,
                                              const float* __restrict__ vit,
                                              float* __restrict__ part) {
    __shared__ __align__(16) float sXT[128*68];       // [n][c], pitch 68
    int t = threadIdx.x;
    int blk = blockIdx.x;
    int ch = blk & 31, b = (blk >> 5) & 3, i2 = blk >> 7;
    const float* X = (i2 ? vit : cnn) + b * CN;
    int n0 = ch * 128;
#pragma unroll
    for (int j = 0; j < 8; j++) {
        int idx = t + j * 256;                        // 0..2047
        int c = idx >> 5, n4 = idx & 31;
        f4v val = *(const f4v*)&X[c * NN + n0 + n4 * 4];
        int base = (n4 * 4) * 68 + c;
        sXT[base]       = val[0];
        sXT[base + 68]  = val[1];
        sXT[base + 136] = val[2];
        sXT[base + 204] = val[3];
    }
    __syncthreads();
    int tc = (t & 15) * 4, td = (t >> 4) * 4;
    f4v acc[4];
#pragma unroll
    for (int i = 0; i < 4; i++) acc[i] = (f4v){0.f, 0.f, 0.f, 0.f};
#pragma unroll 4
    for (int k = 0; k < 128; k++) {
        f4v a  = *(const f4v*)&sXT[k * 68 + tc];
        f4v bb = *(const f4v*)&sXT[k * 68 + td];
#pragma unroll
        for (int i = 0; i < 4; i++) acc[i] += a[i] * bb;
    }
    float* dst = part + ch * 32768 + (i2 * 4 + b) * 4096;
#pragma unroll
    for (int i = 0; i < 4; i++) *(f4v*)&dst[(tc + i) * 64 + td] = acc[i];
}

// ---------------------------------------------------------------------------
// K2: reduce 32 gram partials + fused channel softmax (exp(min-x)/sum form).
__global__ void gred_k(const float* __restrict__ part, float* __restrict__ G) {
    int row = blockIdx.x;                             // 512 = 2*B*C
    int d = threadIdx.x;                              // 64
    float s = 0.f;
#pragma unroll 8
    for (int ch = 0; ch < 32; ch++) s += part[ch * 32768 + row * 64 + d];
    float mn = s;
#pragma unroll
    for (int off = 1; off < 64; off <<= 1) mn = fminf(mn, __shfl_xor(mn, off));
    float e = __expf(mn - s);
    float sm = e;
#pragma unroll
    for (int off = 1; off < 64; off <<= 1) sm += __shfl_xor(sm, off);
    G[row * 64 + d] = e / sm;
}

// ---------------------------------------------------------------------------
// K3: effective weights + bf16 MFMA-A-fragment pack. grid 20 = (b:4, tile:5).
__global__ __launch_bounds__(256) void weff_k(const float* __restrict__ G,
                                              const float* __restrict__ Wq,
                                              const float* __restrict__ Wk,
                                              const float* __restrict__ Wv,
                                              const float* __restrict__ gcnn,
                                              const float* __restrict__ gvit,
                                              ushort* __restrict__ WeffB) {
    __shared__ float sA[8192];                        // Gc | Gv  (A[d][c])
    __shared__ float sWt[1024];                       // this tile's 16x64 fp32
    int t = threadIdx.x;
    int b = blockIdx.x / 5, tile = blockIdx.x % 5;
    for (int i = t; i < 4096; i += 256) {
        sA[i]        = G[b * 4096 + i];
        sA[4096 + i] = G[(4 + b) * 4096 + i];
    }
    __syncthreads();
    float gc = *gcnn, gv = *gvit;
#pragma unroll
    for (int k = 0; k < 4; k++) {
        int idx = k * 256 + t;                        // 0..1023
        int r = idx >> 6, c = idx & 63;
        const float* Wrow; const float* A; float g;
        if (tile == 0) {
            if (r < 8) { Wrow = Wq + r * 64;       A = sA;        g = gc; }
            else       { Wrow = Wk + (r - 8) * 64; A = sA + 4096; g = gv; }
        } else         { Wrow = Wv + ((tile - 1) * 16 + r) * 64; A = sA + 4096; g = gv; }
        float s = 0.f;
#pragma unroll 8
        for (int d = 0; d < 64; d++) s += Wrow[d] * A[d * 64 + c];
        sWt[idx] = g * s + Wrow[c];
    }
    __syncthreads();
    if (t < 128) {
        int frag = t >> 6, lane = t & 63, m = lane & 15, q4 = lane >> 4;
        i4v o;
#pragma unroll
        for (int p = 0; p < 4; p++) {
            int c0 = frag * 32 + q4 * 8 + 2 * p;
            o[p] = (int)pack_bf16(sWt[m * 64 + c0], sWt[m * 64 + c0 + 1]);
        }
        *(i4v*)&WeffB[(size_t)(b * 10 + tile * 2 + frag) * 512 + lane * 8] = o;
    }
}

// ---------------------------------------------------------------------------
// K4: MFMA QKV projections. grid 256 = (b:4, nchunk:64). q scaled by log2e.
// R3: V is emitted DIRECTLY in the flash PV A-fragment layout
// vF[(b*64+ktg)*8 + nt*2 + F][lane][8] via a one-time LDS transpose, so the
// flash kernel needs no LDS staging at all. k-permutation within a frag:
// k = 32F + 16*(e>>2) + 4*q4 + (e&3)  (bit-identical to the old pi-permuted
// LDS read; same truncating f32->bf16 pack).
__global__ __launch_bounds__(256) void qkv_k(const float* __restrict__ cnn,
                                             const float* __restrict__ vit,
                                             const ushort* __restrict__ WeffB,
                                             const float* __restrict__ bq,
                                             const float* __restrict__ bk,
                                             const float* __restrict__ bv,
                                             ushort* __restrict__ qb, ushort* __restrict__ kb,
                                             ushort* __restrict__ vF) {
    __shared__ float vbuf[64 * 67];                   // [c][n_local], pitch 67
    int t = threadIdx.x;
    int b = blockIdx.x >> 6, ktg = blockIdx.x & 63, n0 = ktg * 64;
    int w = t >> 6, lane = t & 63, c15 = lane & 15, q4 = lane >> 4;
    int n = n0 + w * 16 + c15;
    const float LOG2E = 1.44269504f;

    s8v A[10];
    const ushort* WB = WeffB + (size_t)b * 5120 + lane * 8;
#pragma unroll
    for (int i = 0; i < 10; i++)
        A[i] = __builtin_bit_cast(s8v, *(const i4v*)(WB + (size_t)i * 512));

    s8v Bc[2], Bv[2];
#pragma unroll
    for (int f = 0; f < 2; f++) {
        i4v pc, pv;
#pragma unroll
        for (int p = 0; p < 4; p++) {
            int c0 = f * 32 + q4 * 8 + p * 2;
            size_t a0 = (size_t)b * CN + (size_t)c0 * NN + n;
            pc[p] = (int)pack_bf16(cnn[a0], cnn[a0 + NN]);
            pv[p] = (int)pack_bf16(vit[a0], vit[a0 + NN]);
        }
        Bc[f] = __builtin_bit_cast(s8v, pc);
        Bv[f] = __builtin_bit_cast(s8v, pv);
    }

    // q rows (scaled by log2e)
    f4v acc = *(const f4v*)(bq + (q4 & 1) * 4);
    acc = __builtin_amdgcn_mfma_f32_16x16x32_bf16(A[0], Bc[0], acc, 0, 0, 0);
    acc = __builtin_amdgcn_mfma_f32_16x16x32_bf16(A[1], Bc[1], acc, 0, 0, 0);
    if (q4 < 2) {
        unsigned d0 = pack_bf16(acc[0] * LOG2E, acc[1] * LOG2E);
        unsigned d1 = pack_bf16(acc[2] * LOG2E, acc[3] * LOG2E);
        unsigned long long v = ((unsigned long long)d1 << 32) | d0;
        *(unsigned long long*)&qb[(size_t)(b * NN + n) * 8 + q4 * 4] = v;
    }
    // k rows
    acc = *(const f4v*)(bk + (q4 & 1) * 4);
    acc = __builtin_amdgcn_mfma_f32_16x16x32_bf16(A[0], Bv[0], acc, 0, 0, 0);
    acc = __builtin_amdgcn_mfma_f32_16x16x32_bf16(A[1], Bv[1], acc, 0, 0, 0);
    if (q4 >= 2) {
        unsigned d0 = pack_bf16(acc[0], acc[1]), d1 = pack_bf16(acc[2], acc[3]);
        unsigned long long v = ((unsigned long long)d1 << 32) | d0;
        *(unsigned long long*)&kb[(size_t)(b * NN + n) * 8 + (q4 - 2) * 4] = v;
    }
    // v rows -> f32 staging in LDS [c][n_local]
#pragma unroll
    for (int tile = 1; tile < 5; tile++) {
        acc = *(const f4v*)(bv + (tile - 1) * 16 + q4 * 4);
        acc = __builtin_amdgcn_mfma_f32_16x16x32_bf16(A[tile * 2],     Bv[0], acc, 0, 0, 0);
        acc = __builtin_amdgcn_mfma_f32_16x16x32_bf16(A[tile * 2 + 1], Bv[1], acc, 0, 0, 0);
#pragma unroll
        for (int r = 0; r < 4; r++)
            vbuf[((tile - 1) * 16 + q4 * 4 + r) * 67 + w * 16 + c15] = acc[r];
    }
    __syncthreads();
    // emit A-frag layout: thread -> (nt = w, lane l); 16B per F, coalesced.
    {
        int nt = w, l = lane, q4f = q4, c15f = c15;
#pragma unroll
        for (int F = 0; F < 2; F++) {
            float vv[8];
#pragma unroll
            for (int e = 0; e < 8; e++)
                vv[e] = vbuf[(nt * 16 + c15f) * 67 + 32 * F + 16 * (e >> 2)
                             + 4 * q4f + (e & 3)];
            i4v o;
#pragma unroll
            for (int p = 0; p < 4; p++)
                o[p] = (int)pack_bf16(vv[2 * p], vv[2 * p + 1]);
            *(i4v*)&vF[((size_t)((b * 64 + ktg) * 8 + nt * 2 + F)) * 512 + l * 8] = o;
        }
    }
}

// ---------------------------------------------------------------------------
// K5: barrier-free flash + fused epilogue. grid 256 = (b:4, qc:64 of 64 q),
// 256 threads = 4 waves. Wave w owns k-quarter w*1024..+1023 (16 kt of 64 k)
// for ALL 64 q (g=4 q-frags -> each V-frag load feeds 4 PV MFMAs). V and K
// fragments are read directly from L2 (vF is 512KB/batch: cache-resident;
// no LDS staging, no k-loop barriers). 3-barrier LDS combine at the end,
// out = gamma*O/L + cnn written straight from the block.
__global__ __launch_bounds__(256, 2) void flashB(
        const ushort* __restrict__ qb, const ushort* __restrict__ kb,
        const ushort* __restrict__ vF, const float* __restrict__ cnn,
        const float* __restrict__ gamma, float* __restrict__ out) {
    __shared__ __align__(16) float sO[2][64 * 68];    // two 17KB slabs
    __shared__ float sL[4][64];
    __shared__ float sRv[64];

    int t = threadIdx.x;
    int lane = t & 63, w = t >> 6;                    // wave 0..3
    int c15 = lane & 15, q4 = lane >> 4;
    int blk = blockIdx.x;
    int b = blk >> 6, q0 = (blk & 63) * 64;
    float gm = *gamma;

    // Q frags for the block's 64 q (only q4==0 lanes carry features, C8=8)
    s8v qB[4];
#pragma unroll
    for (int g = 0; g < 4; g++) {
        i4v qa = (i4v){0, 0, 0, 0};
        if (q4 == 0)
            qa = *(const i4v*)(qb + (size_t)(b * NN + q0 + g * 16 + c15) * 8);
        qB[g] = __builtin_bit_cast(s8v, qa);
    }

    f4v accO[4][4];
#pragma unroll
    for (int g = 0; g < 4; g++)
#pragma unroll
        for (int nt = 0; nt < 4; nt++) accO[g][nt] = (f4v){0.f, 0.f, 0.f, 0.f};
    float lacc[4] = {0.f, 0.f, 0.f, 0.f};

    const ushort* kbb = kb + (size_t)b * NN * 8 + (size_t)c15 * 8;
    const ushort* vfb = vF + (size_t)b * 64 * 8 * 512 + (size_t)lane * 8;
    int kq = w * 1024;                                // wave's k-base

    // preload K for kt0
    i4v bkc[4];
#pragma unroll
    for (int nt = 0; nt < 4; nt++)
        bkc[nt] = *(const i4v*)(kbb + (size_t)(kq + nt * 16) * 8);

    for (int kt = 0; kt < 16; kt++) {
        int ktg = (kq >> 6) + kt;
        // V frags for this kt: 8 coalesced 1KB wave-loads from L2.
        i4v vA[2][4];
#pragma unroll
        for (int F = 0; F < 2; F++)
#pragma unroll
            for (int nt = 0; nt < 4; nt++)
                vA[F][nt] = *(const i4v*)(vfb +
                    (size_t)(ktg * 8 + nt * 2 + F) * 512);
        // prefetch next K
        i4v bkn[4];
        if (kt < 15) {
#pragma unroll
            for (int nt = 0; nt < 4; nt++)
                bkn[nt] = *(const i4v*)(kbb +
                    (size_t)(kq + (kt + 1) * 64 + nt * 16) * 8);
        }

#pragma unroll
        for (int g = 0; g < 4; g++) {
            f4v z = (f4v){0.f, 0.f, 0.f, 0.f};
            f4v S[4];
#pragma unroll
            for (int nt = 0; nt < 4; nt++)
                S[nt] = __builtin_amdgcn_mfma_f32_16x16x32_bf16(
                    __builtin_bit_cast(s8v, bkc[nt]), qB[g], z, 0, 0, 0);
            f4v p[4];
            float ps = 0.f;
#pragma unroll
            for (int nt = 0; nt < 4; nt++)
#pragma unroll
                for (int rr = 0; rr < 4; rr++) {
                    p[nt][rr] = __builtin_amdgcn_exp2f(S[nt][rr]);
                    ps += p[nt][rr];
                }
            lacc[g] += ps;
            s8v Bp[2];
#pragma unroll
            for (int F = 0; F < 2; F++) {
                i4v bp;
                bp[0] = (int)pack2(p[2 * F][0],     p[2 * F][1]);
                bp[1] = (int)pack2(p[2 * F][2],     p[2 * F][3]);
                bp[2] = (int)pack2(p[2 * F + 1][0], p[2 * F + 1][1]);
                bp[3] = (int)pack2(p[2 * F + 1][2], p[2 * F + 1][3]);
                Bp[F] = __builtin_bit_cast(s8v, bp);
            }
            __builtin_amdgcn_s_setprio(1);
#pragma unroll
            for (int F = 0; F < 2; F++)
#pragma unroll
                for (int nt = 0; nt < 4; nt++)
                    accO[g][nt] = __builtin_amdgcn_mfma_f32_16x16x32_bf16(
                        __builtin_bit_cast(s8v, vA[F][nt]), Bp[F],
                        accO[g][nt], 0, 0, 0);
            __builtin_amdgcn_s_setprio(0);
        }
        if (kt < 15) {
#pragma unroll
            for (int nt = 0; nt < 4; nt++) bkc[nt] = bkn[nt];
        }
    }

    // per-wave L for its k-range (reduce over q4 groups)
#pragma unroll
    for (int g = 0; g < 4; g++) {
        lacc[g] += __shfl_xor(lacc[g], 16);
        lacc[g] += __shfl_xor(lacc[g], 32);
        if (q4 == 0) sL[w][g * 16 + c15] = lacc[g];
    }
    // cross-wave combine: w2->slab0, w3->slab1
    if (w >= 2) {
        float* s = sO[w - 2];
#pragma unroll
        for (int g = 0; g < 4; g++)
#pragma unroll
            for (int nt = 0; nt < 4; nt++)
#pragma unroll
                for (int rr = 0; rr < 4; rr++)
                    s[(nt * 16 + q4 * 4 + rr) * 68 + g * 16 + c15] = accO[g][nt][rr];
    }
    __syncthreads();                                  // #1
    if (w < 2) {
        float* s = sO[w];
#pragma unroll
        for (int g = 0; g < 4; g++)
#pragma unroll
            for (int nt = 0; nt < 4; nt++)
#pragma unroll
                for (int rr = 0; rr < 4; rr++)
                    accO[g][nt][rr] += s[(nt * 16 + q4 * 4 + rr) * 68 + g * 16 + c15];
    }
    if (w == 1) {
        float* s = sO[1];
#pragma unroll
        for (int g = 0; g < 4; g++)
#pragma unroll
            for (int nt = 0; nt < 4; nt++)
#pragma unroll
                for (int rr = 0; rr < 4; rr++)
                    s[(nt * 16 + q4 * 4 + rr) * 68 + g * 16 + c15] = accO[g][nt][rr];
    }
    if (w == 2) {                                     // rv = gamma / L  (q = lane)
        float Ls = sL[0][lane] + sL[1][lane] + sL[2][lane] + sL[3][lane];
        sRv[lane] = gm / Ls;
    }
    __syncthreads();                                  // #2
    if (w == 0) {
        float* s1 = sO[1];
        float* s0 = sO[0];
#pragma unroll
        for (int g = 0; g < 4; g++)
#pragma unroll
            for (int nt = 0; nt < 4; nt++)
#pragma unroll
                for (int rr = 0; rr < 4; rr++) {
                    int off = (nt * 16 + q4 * 4 + rr) * 68 + g * 16 + c15;
                    s0[off] = accO[g][nt][rr] + s1[off];
                }
    }
    __syncthreads();                                  // #3
    // epilogue: out = O*rv + cnn, coalesced 256B rows
#pragma unroll
    for (int it = 0; it < 4; it++) {
        int c = it * 16 + (t >> 4), l16 = t & 15, q = l16 * 4;
        f4v o  = *(const f4v*)&sO[0][c * 68 + q];
        f4v rv = *(const f4v*)&sRv[q];
        size_t gi = (size_t)(b * 64 + c) * NN + q0 + q;
        f4v cv = *(const f4v*)&cnn[gi];
        *(f4v*)&out[gi] = o * rv + cv;
    }
}

// ---------------------------------------------------------------------------
extern "C" void kernel_launch(void* const* d_in, const int* in_sizes, int n_in,
                              void* d_out, int out_size, void* d_ws, size_t ws_size,
                              hipStream_t stream) {
    const float* cnn  = (const float*)d_in[0];
    const float* vit  = (const float*)d_in[1];
    const float* Wq   = (const float*)d_in[2];
    const float* bq   = (const float*)d_in[3];
    const float* Wk   = (const float*)d_in[4];
    const float* bk   = (const float*)d_in[5];
    const float* Wv   = (const float*)d_in[6];
    const float* bv   = (const float*)d_in[7];
    const float* gam  = (const float*)d_in[8];
    const float* gcnn = (const float*)d_in[9];
    const float* gvit = (const float*)d_in[10];
    float* out = (float*)d_out;

    float* ws = (float*)d_ws;
    float*  part  = ws;                          // 1,048,576 f (4 MB)
    float*  G     = ws + 1048576;                // 32,768 f
    ushort* WeffB = (ushort*)(ws + 1081344);     // 20,480 bf16
    ushort* qb    = (ushort*)(ws + 1091584);     // 131,072 bf16
    ushort* kb    = (ushort*)(ws + 1157120);     // 131,072 bf16
    ushort* vF    = (ushort*)(ws + 1222656);     // 1,048,576 bf16 (frag layout)

    gram_k<<<256, 256, 0, stream>>>(cnn, vit, part);
    gred_k<<<512, 64,  0, stream>>>(part, G);
    weff_k<<<20,  256, 0, stream>>>(G, Wq, Wk, Wv, gcnn, gvit, WeffB);
    qkv_k <<<256, 256, 0, stream>>>(cnn, vit, WeffB, bq, bk, bv, qb, kb, vF);
    flashB<<<256, 256, 0, stream>>>(qb, kb, vF, cnn, gam, out);
}

// Round 4
// 122.964 us; speedup vs baseline: 1.7574x; 1.0177x over previous
//
#include <hip/hip_runtime.h>
#include <hip/hip_bf16.h>

#define BSZ 4
#define CC 64
#define NN 4096
#define CN (CC*NN)        // 262144
#define BCN (BSZ*CN)      // 1048576

typedef __attribute__((ext_vector_type(4))) float    f4v;
typedef __attribute__((ext_vector_type(4))) int      i4v;
typedef __attribute__((ext_vector_type(2))) int      i2v;
typedef __attribute__((ext_vector_type(8))) short    s8v;

__device__ __forceinline__ unsigned pack_bf16(float lo, float hi) {
    unsigned l = __builtin_bit_cast(unsigned, lo);
    unsigned h = __builtin_bit_cast(unsigned, hi);
    return (h & 0xFFFF0000u) | (l >> 16);
}
// single v_cvt_pk_bf16_f32 (RNE)
__device__ __forceinline__ unsigned pack2(float lo, float hi) {
    float2 f2; f2.x = lo; f2.y = hi;
    __hip_bfloat162 h = __float22bfloat162_rn(f2);
    unsigned u;
    __builtin_memcpy(&u, &h, 4);
    return u;
}

// ---------------------------------------------------------------------------
// K1: gram partials, 128-wide n-chunks. grid 256 = (i2:2, b:4, chunk:32).
// X staged transposed in LDS, 4x4 register tile per thread; k-loop unroll 4.
__global__ __launch_bounds__(256) void gram_k(const float* __restrict__ cnn,
                                              const float* __restrict__ vit,
                                              float* __restrict__ part) {
    __shared__ __align__(16) float sXT[128*68];       // [n][c], pitch 68
    int t = threadIdx.x;
    int blk = blockIdx.x;
    int ch = blk & 31, b = (blk >> 5) & 3, i2 = blk >> 7;
    const float* X = (i2 ? vit : cnn) + b * CN;
    int n0 = ch * 128;
#pragma unroll
    for (int j = 0; j < 8; j++) {
        int idx = t + j * 256;                        // 0..2047
        int c = idx >> 5, n4 = idx & 31;
        f4v val = *(const f4v*)&X[c * NN + n0 + n4 * 4];
        int base = (n4 * 4) * 68 + c;
        sXT[base]       = val[0];
        sXT[base + 68]  = val[1];
        sXT[base + 136] = val[2];
        sXT[base + 204] = val[3];
    }
    __syncthreads();
    int tc = (t & 15) * 4, td = (t >> 4) * 4;
    f4v acc[4];
#pragma unroll
    for (int i = 0; i < 4; i++) acc[i] = (f4v){0.f, 0.f, 0.f, 0.f};
#pragma unroll 4
    for (int k = 0; k < 128; k++) {
        f4v a  = *(const f4v*)&sXT[k * 68 + tc];
        f4v bb = *(const f4v*)&sXT[k * 68 + td];
#pragma unroll
        for (int i = 0; i < 4; i++) acc[i] += a[i] * bb;
    }
    float* dst = part + ch * 32768 + (i2 * 4 + b) * 4096;
#pragma unroll
    for (int i = 0; i < 4; i++) *(f4v*)&dst[(tc + i) * 64 + td] = acc[i];
}

// ---------------------------------------------------------------------------
// K2: reduce 32 gram partials + fused channel softmax (exp(min-x)/sum form).
__global__ void gred_k(const float* __restrict__ part, float* __restrict__ G) {
    int row = blockIdx.x;                             // 512 = 2*B*C
    int d = threadIdx.x;                              // 64
    float s = 0.f;
#pragma unroll 8
    for (int ch = 0; ch < 32; ch++) s += part[ch * 32768 + row * 64 + d];
    float mn = s;
#pragma unroll
    for (int off = 1; off < 64; off <<= 1) mn = fminf(mn, __shfl_xor(mn, off));
    float e = __expf(mn - s);
    float sm = e;
#pragma unroll
    for (int off = 1; off < 64; off <<= 1) sm += __shfl_xor(sm, off);
    G[row * 64 + d] = e / sm;
}

// ---------------------------------------------------------------------------
// K3 (R4): weff FUSED into qkv — each block recomputes its b's 80x64 Weff
// (Weff = g*(W·A)+W, exact fold) from G, loop-hoisted: per thread 128 LDS
// reads + 1280 FMA for 20 outputs (acc[mi][tile]); sWt pitch-65 kills the
// m*64 bank conflict on the frag-pack reads. Then identical MFMA QKV body;
// V emitted directly in flash PV A-frag layout (bit-identical mapping).
__global__ __launch_bounds__(256) void qkvw_k(const float* __restrict__ cnn,
                                              const float* __restrict__ vit,
                                              const float* __restrict__ G,
                                              const float* __restrict__ Wq,
                                              const float* __restrict__ Wk,
                                              const float* __restrict__ Wv,
                                              const float* __restrict__ gcnn,
                                              const float* __restrict__ gvit,
                                              const float* __restrict__ bq,
                                              const float* __restrict__ bk,
                                              const float* __restrict__ bv,
                                              ushort* __restrict__ qb,
                                              ushort* __restrict__ kb,
                                              ushort* __restrict__ vF) {
    __shared__ __align__(16) float sA[8192];          // Gc | Gv ; later vbuf
    __shared__ float sWt[5200];                       // 5 tiles, pitch 65
    int t = threadIdx.x;
    int b = blockIdx.x >> 6, ktg = blockIdx.x & 63, n0 = ktg * 64;
    int w = t >> 6, lane = t & 63, c15 = lane & 15, q4 = lane >> 4;
    int n = n0 + w * 16 + c15;
    const float LOG2E = 1.44269504f;

    // ---- stage G (A-matrices) ----
#pragma unroll
    for (int i = 0; i < 4; i++) {
        int idx = (i * 256 + t) * 4;
        *(f4v*)&sA[idx]        = *(const f4v*)&G[(size_t)b * 4096 + idx];
        *(f4v*)&sA[4096 + idx] = *(const f4v*)&G[(size_t)(4 + b) * 4096 + idx];
    }
    __syncthreads();

    // ---- Weff: thread (r16 = t>>6, c = t&63) computes rows m = mi*4+r16 ----
    {
        int r16 = w, c = t & 63;
        float gc = *gcnn, gv = *gvit;
        float acc[4][5];
#pragma unroll
        for (int mi = 0; mi < 4; mi++)
#pragma unroll
            for (int tl = 0; tl < 5; tl++) acc[mi][tl] = 0.f;
#pragma unroll 4
        for (int d = 0; d < 64; d++) {
            float av = sA[4096 + d * 64 + c];
            float ac = sA[d * 64 + c];
#pragma unroll
            for (int mi = 0; mi < 4; mi++) {
                int m = mi * 4 + r16;
                if (mi < 2)
                    acc[mi][0] += Wq[m * 64 + d] * ac;        // m<8: Wq row
                else
                    acc[mi][0] += Wk[(m - 8) * 64 + d] * av;  // m>=8: Wk row
#pragma unroll
                for (int tl = 1; tl < 5; tl++)
                    acc[mi][tl] += Wv[((tl - 1) * 16 + m) * 64 + d] * av;
            }
        }
#pragma unroll
        for (int mi = 0; mi < 4; mi++) {
            int m = mi * 4 + r16;
            if (mi < 2)
                sWt[m * 65 + c] = gc * acc[mi][0] + Wq[m * 64 + c];
            else
                sWt[m * 65 + c] = gv * acc[mi][0] + Wk[(m - 8) * 64 + c];
#pragma unroll
            for (int tl = 1; tl < 5; tl++)
                sWt[tl * 1040 + m * 65 + c] =
                    gv * acc[mi][tl] + Wv[((tl - 1) * 16 + m) * 64 + c];
        }
    }
    __syncthreads();

    // ---- A-frag pack from sWt (pitch 65: conflict-free) ----
    s8v A[10];
#pragma unroll
    for (int i = 0; i < 10; i++) {
        int tile = i >> 1, frag = i & 1;
        const float* src = &sWt[tile * 1040 + (lane & 15) * 65 + frag * 32 + q4 * 8];
        i4v o;
#pragma unroll
        for (int p = 0; p < 4; p++)
            o[p] = (int)pack_bf16(src[2 * p], src[2 * p + 1]);
        A[i] = __builtin_bit_cast(s8v, o);
    }

    // ---- B-frag packs from inputs ----
    s8v Bc[2], Bv[2];
#pragma unroll
    for (int f = 0; f < 2; f++) {
        i4v pc, pv;
#pragma unroll
        for (int p = 0; p < 4; p++) {
            int c0 = f * 32 + q4 * 8 + p * 2;
            size_t a0 = (size_t)b * CN + (size_t)c0 * NN + n;
            pc[p] = (int)pack_bf16(cnn[a0], cnn[a0 + NN]);
            pv[p] = (int)pack_bf16(vit[a0], vit[a0 + NN]);
        }
        Bc[f] = __builtin_bit_cast(s8v, pc);
        Bv[f] = __builtin_bit_cast(s8v, pv);
    }

    // q rows (scaled by log2e)
    f4v acc = *(const f4v*)(bq + (q4 & 1) * 4);
    acc = __builtin_amdgcn_mfma_f32_16x16x32_bf16(A[0], Bc[0], acc, 0, 0, 0);
    acc = __builtin_amdgcn_mfma_f32_16x16x32_bf16(A[1], Bc[1], acc, 0, 0, 0);
    if (q4 < 2) {
        unsigned d0 = pack_bf16(acc[0] * LOG2E, acc[1] * LOG2E);
        unsigned d1 = pack_bf16(acc[2] * LOG2E, acc[3] * LOG2E);
        unsigned long long v = ((unsigned long long)d1 << 32) | d0;
        *(unsigned long long*)&qb[(size_t)(b * NN + n) * 8 + q4 * 4] = v;
    }
    // k rows
    acc = *(const f4v*)(bk + (q4 & 1) * 4);
    acc = __builtin_amdgcn_mfma_f32_16x16x32_bf16(A[0], Bv[0], acc, 0, 0, 0);
    acc = __builtin_amdgcn_mfma_f32_16x16x32_bf16(A[1], Bv[1], acc, 0, 0, 0);
    if (q4 >= 2) {
        unsigned d0 = pack_bf16(acc[0], acc[1]), d1 = pack_bf16(acc[2], acc[3]);
        unsigned long long v = ((unsigned long long)d1 << 32) | d0;
        *(unsigned long long*)&kb[(size_t)(b * NN + n) * 8 + (q4 - 2) * 4] = v;
    }
    // v rows -> f32 staging in LDS [c][n_local] (vbuf aliases sA, now dead)
    float* vbuf = sA;
#pragma unroll
    for (int tile = 1; tile < 5; tile++) {
        acc = *(const f4v*)(bv + (tile - 1) * 16 + q4 * 4);
        acc = __builtin_amdgcn_mfma_f32_16x16x32_bf16(A[tile * 2],     Bv[0], acc, 0, 0, 0);
        acc = __builtin_amdgcn_mfma_f32_16x16x32_bf16(A[tile * 2 + 1], Bv[1], acc, 0, 0, 0);
#pragma unroll
        for (int r = 0; r < 4; r++)
            vbuf[((tile - 1) * 16 + q4 * 4 + r) * 67 + w * 16 + c15] = acc[r];
    }
    __syncthreads();
    // emit PV A-frag layout (k = 32F + 16*(e>>2) + 4*q4 + (e&3))
    {
        int nt = w;
#pragma unroll
        for (int F = 0; F < 2; F++) {
            float vv[8];
#pragma unroll
            for (int e = 0; e < 8; e++)
                vv[e] = vbuf[(nt * 16 + c15) * 67 + 32 * F + 16 * (e >> 2)
                             + 4 * q4 + (e & 3)];
            i4v o;
#pragma unroll
            for (int p = 0; p < 4; p++)
                o[p] = (int)pack_bf16(vv[2 * p], vv[2 * p + 1]);
            *(i4v*)&vF[((size_t)((b * 64 + ktg) * 8 + nt * 2 + F)) * 512 + lane * 8] = o;
        }
    }
}

// ---------------------------------------------------------------------------
// K4: barrier-free flash + fused epilogue (unchanged from R3).
__global__ __launch_bounds__(256, 2) void flashB(
        const ushort* __restrict__ qb, const ushort* __restrict__ kb,
        const ushort* __restrict__ vF, const float* __restrict__ cnn,
        const float* __restrict__ gamma, float* __restrict__ out) {
    __shared__ __align__(16) float sO[2][64 * 68];    // two 17KB slabs
    __shared__ float sL[4][64];
    __shared__ float sRv[64];

    int t = threadIdx.x;
    int lane = t & 63, w = t >> 6;                    // wave 0..3
    int c15 = lane & 15, q4 = lane >> 4;
    int blk = blockIdx.x;
    int b = blk >> 6, q0 = (blk & 63) * 64;
    float gm = *gamma;

    s8v qB[4];
#pragma unroll
    for (int g = 0; g < 4; g++) {
        i4v qa = (i4v){0, 0, 0, 0};
        if (q4 == 0)
            qa = *(const i4v*)(qb + (size_t)(b * NN + q0 + g * 16 + c15) * 8);
        qB[g] = __builtin_bit_cast(s8v, qa);
    }

    f4v accO[4][4];
#pragma unroll
    for (int g = 0; g < 4; g++)
#pragma unroll
        for (int nt = 0; nt < 4; nt++) accO[g][nt] = (f4v){0.f, 0.f, 0.f, 0.f};
    float lacc[4] = {0.f, 0.f, 0.f, 0.f};

    const ushort* kbb = kb + (size_t)b * NN * 8 + (size_t)c15 * 8;
    const ushort* vfb = vF + (size_t)b * 64 * 8 * 512 + (size_t)lane * 8;
    int kq = w * 1024;                                // wave's k-base

    i4v bkc[4];
#pragma unroll
    for (int nt = 0; nt < 4; nt++)
        bkc[nt] = *(const i4v*)(kbb + (size_t)(kq + nt * 16) * 8);

    for (int kt = 0; kt < 16; kt++) {
        int ktg = (kq >> 6) + kt;
        i4v vA[2][4];
#pragma unroll
        for (int F = 0; F < 2; F++)
#pragma unroll
            for (int nt = 0; nt < 4; nt++)
                vA[F][nt] = *(const i4v*)(vfb +
                    (size_t)(ktg * 8 + nt * 2 + F) * 512);
        i4v bkn[4];
        if (kt < 15) {
#pragma unroll
            for (int nt = 0; nt < 4; nt++)
                bkn[nt] = *(const i4v*)(kbb +
                    (size_t)(kq + (kt + 1) * 64 + nt * 16) * 8);
        }

#pragma unroll
        for (int g = 0; g < 4; g++) {
            f4v z = (f4v){0.f, 0.f, 0.f, 0.f};
            f4v S[4];
#pragma unroll
            for (int nt = 0; nt < 4; nt++)
                S[nt] = __builtin_amdgcn_mfma_f32_16x16x32_bf16(
                    __builtin_bit_cast(s8v, bkc[nt]), qB[g], z, 0, 0, 0);
            f4v p[4];
            float ps = 0.f;
#pragma unroll
            for (int nt = 0; nt < 4; nt++)
#pragma unroll
                for (int rr = 0; rr < 4; rr++) {
                    p[nt][rr] = __builtin_amdgcn_exp2f(S[nt][rr]);
                    ps += p[nt][rr];
                }
            lacc[g] += ps;
            s8v Bp[2];
#pragma unroll
            for (int F = 0; F < 2; F++) {
                i4v bp;
                bp[0] = (int)pack2(p[2 * F][0],     p[2 * F][1]);
                bp[1] = (int)pack2(p[2 * F][2],     p[2 * F][3]);
                bp[2] = (int)pack2(p[2 * F + 1][0], p[2 * F + 1][1]);
                bp[3] = (int)pack2(p[2 * F + 1][2], p[2 * F + 1][3]);
                Bp[F] = __builtin_bit_cast(s8v, bp);
            }
            __builtin_amdgcn_s_setprio(1);
#pragma unroll
            for (int F = 0; F < 2; F++)
#pragma unroll
                for (int nt = 0; nt < 4; nt++)
                    accO[g][nt] = __builtin_amdgcn_mfma_f32_16x16x32_bf16(
                        __builtin_bit_cast(s8v, vA[F][nt]), Bp[F],
                        accO[g][nt], 0, 0, 0);
            __builtin_amdgcn_s_setprio(0);
        }
        if (kt < 15) {
#pragma unroll
            for (int nt = 0; nt < 4; nt++) bkc[nt] = bkn[nt];
        }
    }

#pragma unroll
    for (int g = 0; g < 4; g++) {
        lacc[g] += __shfl_xor(lacc[g], 16);
        lacc[g] += __shfl_xor(lacc[g], 32);
        if (q4 == 0) sL[w][g * 16 + c15] = lacc[g];
    }
    if (w >= 2) {
        float* s = sO[w - 2];
#pragma unroll
        for (int g = 0; g < 4; g++)
#pragma unroll
            for (int nt = 0; nt < 4; nt++)
#pragma unroll
                for (int rr = 0; rr < 4; rr++)
                    s[(nt * 16 + q4 * 4 + rr) * 68 + g * 16 + c15] = accO[g][nt][rr];
    }
    __syncthreads();                                  // #1
    if (w < 2) {
        float* s = sO[w];
#pragma unroll
        for (int g = 0; g < 4; g++)
#pragma unroll
            for (int nt = 0; nt < 4; nt++)
#pragma unroll
                for (int rr = 0; rr < 4; rr++)
                    accO[g][nt][rr] += s[(nt * 16 + q4 * 4 + rr) * 68 + g * 16 + c15];
    }
    if (w == 1) {
        float* s = sO[1];
#pragma unroll
        for (int g = 0; g < 4; g++)
#pragma unroll
            for (int nt = 0; nt < 4; nt++)
#pragma unroll
                for (int rr = 0; rr < 4; rr++)
                    s[(nt * 16 + q4 * 4 + rr) * 68 + g * 16 + c15] = accO[g][nt][rr];
    }
    if (w == 2) {
        float Ls = sL[0][lane] + sL[1][lane] + sL[2][lane] + sL[3][lane];
        sRv[lane] = gm / Ls;
    }
    __syncthreads();                                  // #2
    if (w == 0) {
        float* s1 = sO[1];
        float* s0 = sO[0];
#pragma unroll
        for (int g = 0; g < 4; g++)
#pragma unroll
            for (int nt = 0; nt < 4; nt++)
#pragma unroll
                for (int rr = 0; rr < 4; rr++) {
                    int off = (nt * 16 + q4 * 4 + rr) * 68 + g * 16 + c15;
                    s0[off] = accO[g][nt][rr] + s1[off];
                }
    }
    __syncthreads();                                  // #3
#pragma unroll
    for (int it = 0; it < 4; it++) {
        int c = it * 16 + (t >> 4), l16 = t & 15, q = l16 * 4;
        f4v o  = *(const f4v*)&sO[0][c * 68 + q];
        f4v rv = *(const f4v*)&sRv[q];
        size_t gi = (size_t)(b * 64 + c) * NN + q0 + q;
        f4v cv = *(const f4v*)&cnn[gi];
        *(f4v*)&out[gi] = o * rv + cv;
    }
}

// ---------------------------------------------------------------------------
extern "C" void kernel_launch(void* const* d_in, const int* in_sizes, int n_in,
                              void* d_out, int out_size, void* d_ws, size_t ws_size,
                              hipStream_t stream) {
    const float* cnn  = (const float*)d_in[0];
    const float* vit  = (const float*)d_in[1];
    const float* Wq   = (const float*)d_in[2];
    const float* bq   = (const float*)d_in[3];
    const float* Wk   = (const float*)d_in[4];
    const float* bk   = (const float*)d_in[5];
    const float* Wv   = (const float*)d_in[6];
    const float* bv   = (const float*)d_in[7];
    const float* gam  = (const float*)d_in[8];
    const float* gcnn = (const float*)d_in[9];
    const float* gvit = (const float*)d_in[10];
    float* out = (float*)d_out;

    float* ws = (float*)d_ws;
    float*  part = ws;                           // 1,048,576 f (4 MB)
    float*  G    = ws + 1048576;                 // 32,768 f
    ushort* qb   = (ushort*)(ws + 1081344);      // 131,072 bf16
    ushort* kb   = (ushort*)(ws + 1146880);      // 131,072 bf16
    ushort* vF   = (ushort*)(ws + 1212416);      // 1,048,576 bf16 (frag layout)

    gram_k<<<256, 256, 0, stream>>>(cnn, vit, part);
    gred_k<<<512, 64,  0, stream>>>(part, G);
    qkvw_k<<<256, 256, 0, stream>>>(cnn, vit, G, Wq, Wk, Wv, gcnn, gvit,
                                    bq, bk, bv, qb, kb, vF);
    flashB<<<256, 256, 0, stream>>>(qb, kb, vF, cnn, gam, out);
}

// Round 5
// 121.542 us; speedup vs baseline: 1.7780x; 1.0117x over previous
//
#include <hip/hip_runtime.h>
#include <hip/hip_bf16.h>

#define BSZ 4
#define CC 64
#define NN 4096
#define CN (CC*NN)        // 262144
#define BCN (BSZ*CN)      // 1048576

typedef __attribute__((ext_vector_type(4))) float    f4v;
typedef __attribute__((ext_vector_type(4))) int      i4v;
typedef __attribute__((ext_vector_type(2))) int      i2v;
typedef __attribute__((ext_vector_type(8))) short    s8v;

__device__ __forceinline__ unsigned pack_bf16(float lo, float hi) {
    unsigned l = __builtin_bit_cast(unsigned, lo);
    unsigned h = __builtin_bit_cast(unsigned, hi);
    return (h & 0xFFFF0000u) | (l >> 16);
}
// single v_cvt_pk_bf16_f32 (RNE)
__device__ __forceinline__ unsigned pack2(float lo, float hi) {
    float2 f2; f2.x = lo; f2.y = hi;
    __hip_bfloat162 h = __float22bfloat162_rn(f2);
    unsigned u;
    __builtin_memcpy(&u, &h, 4);
    return u;
}

// ---------------------------------------------------------------------------
// K1: gram partials, 128-wide n-chunks. grid 256 = (i2:2, b:4, chunk:32).
// X staged transposed in LDS, 4x4 register tile per thread; k-loop unroll 4.
// R5: output tile restaged through LDS (pitch 65) -> flat-contiguous 16 KB
// store per tile: part[((i2*4+b)*32+ch)*4096 + r*64 + d], fully coalesced
// (old path: 16B lane-stores at 1KB stride ~ 2x HBM write amplification).
__global__ __launch_bounds__(256) void gram_k(const float* __restrict__ cnn,
                                              const float* __restrict__ vit,
                                              float* __restrict__ part) {
    __shared__ __align__(16) float sXT[128*68];       // [n][c], pitch 68
    int t = threadIdx.x;
    int blk = blockIdx.x;
    int ch = blk & 31, b = (blk >> 5) & 3, i2 = blk >> 7;
    const float* X = (i2 ? vit : cnn) + b * CN;
    int n0 = ch * 128;
#pragma unroll
    for (int j = 0; j < 8; j++) {
        int idx = t + j * 256;                        // 0..2047
        int c = idx >> 5, n4 = idx & 31;
        f4v val = *(const f4v*)&X[c * NN + n0 + n4 * 4];
        int base = (n4 * 4) * 68 + c;
        sXT[base]       = val[0];
        sXT[base + 68]  = val[1];
        sXT[base + 136] = val[2];
        sXT[base + 204] = val[3];
    }
    __syncthreads();
    int tc = (t & 15) * 4, td = (t >> 4) * 4;
    f4v acc[4];
#pragma unroll
    for (int i = 0; i < 4; i++) acc[i] = (f4v){0.f, 0.f, 0.f, 0.f};
#pragma unroll 4
    for (int k = 0; k < 128; k++) {
        f4v a  = *(const f4v*)&sXT[k * 68 + tc];
        f4v bb = *(const f4v*)&sXT[k * 68 + td];
#pragma unroll
        for (int i = 0; i < 4; i++) acc[i] += a[i] * bb;
    }
    __syncthreads();                                  // sXT reads done
    float* sOut = sXT;                                // reuse, pitch 65
#pragma unroll
    for (int i = 0; i < 4; i++)
        *(f4v*)&sOut[(tc + i) * 65 + td] = acc[i];
    __syncthreads();
    float* dst = part + (size_t)((i2 * 4 + b) * 32 + ch) * 4096;
#pragma unroll
    for (int j = 0; j < 4; j++) {
        int flat = j * 1024 + t * 4;                  // r*64 + d
        int r = flat >> 6, d = flat & 63;
        *(f4v*)&dst[flat] = *(const f4v*)&sOut[r * 65 + d];
    }
}

// ---------------------------------------------------------------------------
// K2 (R5): reduce 32 gram partials + fused channel softmax, f4-vectorized.
// part layout [tile=(i2b,ch)][r*64+d]. Thread (l16 = d-quad, grp = ch%4).
__global__ void gred_k(const float* __restrict__ part, float* __restrict__ G) {
    int R = blockIdx.x;                               // 512 = 2*B*C rows
    int t = threadIdx.x;                              // 64
    int i2b = R >> 6, r = R & 63;
    int l16 = t & 15, grp = t >> 4;
    const float* base = part + (size_t)i2b * 32 * 4096 + r * 64 + l16 * 4;
    f4v s = (f4v){0.f, 0.f, 0.f, 0.f};
#pragma unroll
    for (int c8 = 0; c8 < 8; c8++)
        s += *(const f4v*)(base + (size_t)(c8 * 4 + grp) * 4096);
    // reduce over ch-groups (xor 16, 32): all lanes now hold full sums
#pragma unroll
    for (int off = 16; off < 64; off <<= 1) {
        s[0] += __shfl_xor(s[0], off);
        s[1] += __shfl_xor(s[1], off);
        s[2] += __shfl_xor(s[2], off);
        s[3] += __shfl_xor(s[3], off);
    }
    float mn = fminf(fminf(s[0], s[1]), fminf(s[2], s[3]));
#pragma unroll
    for (int off = 1; off < 16; off <<= 1) mn = fminf(mn, __shfl_xor(mn, off));
    f4v e;
    float sm = 0.f;
#pragma unroll
    for (int j = 0; j < 4; j++) { e[j] = __expf(mn - s[j]); sm += e[j]; }
#pragma unroll
    for (int off = 1; off < 16; off <<= 1) sm += __shfl_xor(sm, off);
    if (t < 16) {
        f4v o;
#pragma unroll
        for (int j = 0; j < 4; j++) o[j] = e[j] / sm;
        *(f4v*)&G[(size_t)R * 64 + l16 * 4] = o;
    }
}

// ---------------------------------------------------------------------------
// K3: weff fused into qkv (unchanged from R4). Each block recomputes its b's
// 80x64 Weff (= g*(W·A)+W) from G; sWt pitch-65; then MFMA QKV body; V
// emitted directly in flash PV A-frag layout.
__global__ __launch_bounds__(256) void qkvw_k(const float* __restrict__ cnn,
                                              const float* __restrict__ vit,
                                              const float* __restrict__ G,
                                              const float* __restrict__ Wq,
                                              const float* __restrict__ Wk,
                                              const float* __restrict__ Wv,
                                              const float* __restrict__ gcnn,
                                              const float* __restrict__ gvit,
                                              const float* __restrict__ bq,
                                              const float* __restrict__ bk,
                                              const float* __restrict__ bv,
                                              ushort* __restrict__ qb,
                                              ushort* __restrict__ kb,
                                              ushort* __restrict__ vF) {
    __shared__ __align__(16) float sA[8192];          // Gc | Gv ; later vbuf
    __shared__ float sWt[5200];                       // 5 tiles, pitch 65
    int t = threadIdx.x;
    int b = blockIdx.x >> 6, ktg = blockIdx.x & 63, n0 = ktg * 64;
    int w = t >> 6, lane = t & 63, c15 = lane & 15, q4 = lane >> 4;
    int n = n0 + w * 16 + c15;
    const float LOG2E = 1.44269504f;

#pragma unroll
    for (int i = 0; i < 4; i++) {
        int idx = (i * 256 + t) * 4;
        *(f4v*)&sA[idx]        = *(const f4v*)&G[(size_t)b * 4096 + idx];
        *(f4v*)&sA[4096 + idx] = *(const f4v*)&G[(size_t)(4 + b) * 4096 + idx];
    }
    __syncthreads();

    {
        int r16 = w, c = t & 63;
        float gc = *gcnn, gv = *gvit;
        float acc[4][5];
#pragma unroll
        for (int mi = 0; mi < 4; mi++)
#pragma unroll
            for (int tl = 0; tl < 5; tl++) acc[mi][tl] = 0.f;
#pragma unroll 4
        for (int d = 0; d < 64; d++) {
            float av = sA[4096 + d * 64 + c];
            float ac = sA[d * 64 + c];
#pragma unroll
            for (int mi = 0; mi < 4; mi++) {
                int m = mi * 4 + r16;
                if (mi < 2)
                    acc[mi][0] += Wq[m * 64 + d] * ac;
                else
                    acc[mi][0] += Wk[(m - 8) * 64 + d] * av;
#pragma unroll
                for (int tl = 1; tl < 5; tl++)
                    acc[mi][tl] += Wv[((tl - 1) * 16 + m) * 64 + d] * av;
            }
        }
#pragma unroll
        for (int mi = 0; mi < 4; mi++) {
            int m = mi * 4 + r16;
            if (mi < 2)
                sWt[m * 65 + c] = gc * acc[mi][0] + Wq[m * 64 + c];
            else
                sWt[m * 65 + c] = gv * acc[mi][0] + Wk[(m - 8) * 64 + c];
#pragma unroll
            for (int tl = 1; tl < 5; tl++)
                sWt[tl * 1040 + m * 65 + c] =
                    gv * acc[mi][tl] + Wv[((tl - 1) * 16 + m) * 64 + c];
        }
    }
    __syncthreads();

    s8v A[10];
#pragma unroll
    for (int i = 0; i < 10; i++) {
        int tile = i >> 1, frag = i & 1;
        const float* src = &sWt[tile * 1040 + (lane & 15) * 65 + frag * 32 + q4 * 8];
        i4v o;
#pragma unroll
        for (int p = 0; p < 4; p++)
            o[p] = (int)pack_bf16(src[2 * p], src[2 * p + 1]);
        A[i] = __builtin_bit_cast(s8v, o);
    }

    s8v Bc[2], Bv[2];
#pragma unroll
    for (int f = 0; f < 2; f++) {
        i4v pc, pv;
#pragma unroll
        for (int p = 0; p < 4; p++) {
            int c0 = f * 32 + q4 * 8 + p * 2;
            size_t a0 = (size_t)b * CN + (size_t)c0 * NN + n;
            pc[p] = (int)pack_bf16(cnn[a0], cnn[a0 + NN]);
            pv[p] = (int)pack_bf16(vit[a0], vit[a0 + NN]);
        }
        Bc[f] = __builtin_bit_cast(s8v, pc);
        Bv[f] = __builtin_bit_cast(s8v, pv);
    }

    f4v acc = *(const f4v*)(bq + (q4 & 1) * 4);
    acc = __builtin_amdgcn_mfma_f32_16x16x32_bf16(A[0], Bc[0], acc, 0, 0, 0);
    acc = __builtin_amdgcn_mfma_f32_16x16x32_bf16(A[1], Bc[1], acc, 0, 0, 0);
    if (q4 < 2) {
        unsigned d0 = pack_bf16(acc[0] * LOG2E, acc[1] * LOG2E);
        unsigned d1 = pack_bf16(acc[2] * LOG2E, acc[3] * LOG2E);
        unsigned long long v = ((unsigned long long)d1 << 32) | d0;
        *(unsigned long long*)&qb[(size_t)(b * NN + n) * 8 + q4 * 4] = v;
    }
    acc = *(const f4v*)(bk + (q4 & 1) * 4);
    acc = __builtin_amdgcn_mfma_f32_16x16x32_bf16(A[0], Bv[0], acc, 0, 0, 0);
    acc = __builtin_amdgcn_mfma_f32_16x16x32_bf16(A[1], Bv[1], acc, 0, 0, 0);
    if (q4 >= 2) {
        unsigned d0 = pack_bf16(acc[0], acc[1]), d1 = pack_bf16(acc[2], acc[3]);
        unsigned long long v = ((unsigned long long)d1 << 32) | d0;
        *(unsigned long long*)&kb[(size_t)(b * NN + n) * 8 + (q4 - 2) * 4] = v;
    }
    float* vbuf = sA;
#pragma unroll
    for (int tile = 1; tile < 5; tile++) {
        acc = *(const f4v*)(bv + (tile - 1) * 16 + q4 * 4);
        acc = __builtin_amdgcn_mfma_f32_16x16x32_bf16(A[tile * 2],     Bv[0], acc, 0, 0, 0);
        acc = __builtin_amdgcn_mfma_f32_16x16x32_bf16(A[tile * 2 + 1], Bv[1], acc, 0, 0, 0);
#pragma unroll
        for (int r = 0; r < 4; r++)
            vbuf[((tile - 1) * 16 + q4 * 4 + r) * 67 + w * 16 + c15] = acc[r];
    }
    __syncthreads();
    {
        int nt = w;
#pragma unroll
        for (int F = 0; F < 2; F++) {
            float vv[8];
#pragma unroll
            for (int e = 0; e < 8; e++)
                vv[e] = vbuf[(nt * 16 + c15) * 67 + 32 * F + 16 * (e >> 2)
                             + 4 * q4 + (e & 3)];
            i4v o;
#pragma unroll
            for (int p = 0; p < 4; p++)
                o[p] = (int)pack_bf16(vv[2 * p], vv[2 * p + 1]);
            *(i4v*)&vF[((size_t)((b * 64 + ktg) * 8 + nt * 2 + F)) * 512 + lane * 8] = o;
        }
    }
}

// ---------------------------------------------------------------------------
// K4 (R5): barrier-free flash, 512 threads / 8 waves (2 waves/SIMD for
// VALU<->MFMA overlap). grid 256 = (b:4, qc:64 of 64 q). Wave w owns
// k-eighth w*512..+511 (8 kt) for all 64 q. Same V-frag/K L2-direct loads.
// 8->1 LDS combine tree (4 slabs, 4 barriers), fused epilogue.
__global__ __launch_bounds__(512, 2) void flashB(
        const ushort* __restrict__ qb, const ushort* __restrict__ kb,
        const ushort* __restrict__ vF, const float* __restrict__ cnn,
        const float* __restrict__ gamma, float* __restrict__ out) {
    __shared__ __align__(16) float sO[4][64 * 68];    // 4 x 17KB slabs
    __shared__ float sL[8][64];
    __shared__ __align__(16) float sRv[64];

    int t = threadIdx.x;
    int lane = t & 63, w = t >> 6;                    // wave 0..7
    int c15 = lane & 15, q4 = lane >> 4;
    int blk = blockIdx.x;
    int b = blk >> 6, q0 = (blk & 63) * 64;
    float gm = *gamma;

    s8v qB[4];
#pragma unroll
    for (int g = 0; g < 4; g++) {
        i4v qa = (i4v){0, 0, 0, 0};
        if (q4 == 0)
            qa = *(const i4v*)(qb + (size_t)(b * NN + q0 + g * 16 + c15) * 8);
        qB[g] = __builtin_bit_cast(s8v, qa);
    }

    f4v accO[4][4];
#pragma unroll
    for (int g = 0; g < 4; g++)
#pragma unroll
        for (int nt = 0; nt < 4; nt++) accO[g][nt] = (f4v){0.f, 0.f, 0.f, 0.f};
    float lacc[4] = {0.f, 0.f, 0.f, 0.f};

    const ushort* kbb = kb + (size_t)b * NN * 8 + (size_t)c15 * 8;
    const ushort* vfb = vF + (size_t)b * 64 * 8 * 512 + (size_t)lane * 8;
    int kq = w * 512;                                 // wave's k-base

    i4v bkc[4];
#pragma unroll
    for (int nt = 0; nt < 4; nt++)
        bkc[nt] = *(const i4v*)(kbb + (size_t)(kq + nt * 16) * 8);

    for (int kt = 0; kt < 8; kt++) {
        int ktg = (kq >> 6) + kt;
        i4v vA[2][4];
#pragma unroll
        for (int F = 0; F < 2; F++)
#pragma unroll
            for (int nt = 0; nt < 4; nt++)
                vA[F][nt] = *(const i4v*)(vfb +
                    (size_t)(ktg * 8 + nt * 2 + F) * 512);
        i4v bkn[4];
        if (kt < 7) {
#pragma unroll
            for (int nt = 0; nt < 4; nt++)
                bkn[nt] = *(const i4v*)(kbb +
                    (size_t)(kq + (kt + 1) * 64 + nt * 16) * 8);
        }

#pragma unroll
        for (int g = 0; g < 4; g++) {
            f4v z = (f4v){0.f, 0.f, 0.f, 0.f};
            f4v S[4];
#pragma unroll
            for (int nt = 0; nt < 4; nt++)
                S[nt] = __builtin_amdgcn_mfma_f32_16x16x32_bf16(
                    __builtin_bit_cast(s8v, bkc[nt]), qB[g], z, 0, 0, 0);
            f4v p[4];
            float ps = 0.f;
#pragma unroll
            for (int nt = 0; nt < 4; nt++)
#pragma unroll
                for (int rr = 0; rr < 4; rr++) {
                    p[nt][rr] = __builtin_amdgcn_exp2f(S[nt][rr]);
                    ps += p[nt][rr];
                }
            lacc[g] += ps;
            s8v Bp[2];
#pragma unroll
            for (int F = 0; F < 2; F++) {
                i4v bp;
                bp[0] = (int)pack2(p[2 * F][0],     p[2 * F][1]);
                bp[1] = (int)pack2(p[2 * F][2],     p[2 * F][3]);
                bp[2] = (int)pack2(p[2 * F + 1][0], p[2 * F + 1][1]);
                bp[3] = (int)pack2(p[2 * F + 1][2], p[2 * F + 1][3]);
                Bp[F] = __builtin_bit_cast(s8v, bp);
            }
            __builtin_amdgcn_s_setprio(1);
#pragma unroll
            for (int F = 0; F < 2; F++)
#pragma unroll
                for (int nt = 0; nt < 4; nt++)
                    accO[g][nt] = __builtin_amdgcn_mfma_f32_16x16x32_bf16(
                        __builtin_bit_cast(s8v, vA[F][nt]), Bp[F],
                        accO[g][nt], 0, 0, 0);
            __builtin_amdgcn_s_setprio(0);
        }
        if (kt < 7) {
#pragma unroll
            for (int nt = 0; nt < 4; nt++) bkc[nt] = bkn[nt];
        }
    }

    // per-wave L partials (lanes sharing q: xor 16, 32)
#pragma unroll
    for (int g = 0; g < 4; g++) {
        lacc[g] += __shfl_xor(lacc[g], 16);
        lacc[g] += __shfl_xor(lacc[g], 32);
        if (q4 == 0) sL[w][g * 16 + c15] = lacc[g];
    }

    // 8->1 combine tree
    auto WRS = [&](float* s) {
#pragma unroll
        for (int g = 0; g < 4; g++)
#pragma unroll
            for (int nt = 0; nt < 4; nt++)
#pragma unroll
                for (int rr = 0; rr < 4; rr++)
                    s[(nt * 16 + q4 * 4 + rr) * 68 + g * 16 + c15] = accO[g][nt][rr];
    };
    auto ADS = [&](const float* s) {
#pragma unroll
        for (int g = 0; g < 4; g++)
#pragma unroll
            for (int nt = 0; nt < 4; nt++)
#pragma unroll
                for (int rr = 0; rr < 4; rr++)
                    accO[g][nt][rr] += s[(nt * 16 + q4 * 4 + rr) * 68 + g * 16 + c15];
    };

    if (w >= 4) WRS(sO[w - 4]);
    __syncthreads();                                  // #1
    if (w < 4)  ADS(sO[w]);
    if (w == 2 || w == 3) WRS(sO[w]);                 // own slab (already read)
    if (w == 4) {                                     // rv = gamma / L
        float Ls = 0.f;
#pragma unroll
        for (int i = 0; i < 8; i++) Ls += sL[i][lane];
        sRv[lane] = gm / Ls;
    }
    __syncthreads();                                  // #2
    if (w == 0) ADS(sO[2]);
    if (w == 1) { ADS(sO[3]); WRS(sO[1]); }
    __syncthreads();                                  // #3
    if (w == 0) { ADS(sO[1]); WRS(sO[0]); }
    __syncthreads();                                  // #4

    // epilogue: out = O*rv + cnn (512 threads, coalesced)
    {
        int c = t >> 3, qo = (t & 7) * 8;
        f4v o0 = *(const f4v*)&sO[0][c * 68 + qo];
        f4v o1 = *(const f4v*)&sO[0][c * 68 + qo + 4];
        f4v r0 = *(const f4v*)&sRv[qo];
        f4v r1 = *(const f4v*)&sRv[qo + 4];
        size_t gi = (size_t)(b * 64 + c) * NN + q0 + qo;
        f4v c0 = *(const f4v*)&cnn[gi];
        f4v c1 = *(const f4v*)&cnn[gi + 4];
        *(f4v*)&out[gi]     = o0 * r0 + c0;
        *(f4v*)&out[gi + 4] = o1 * r1 + c1;
    }
}

// ---------------------------------------------------------------------------
extern "C" void kernel_launch(void* const* d_in, const int* in_sizes, int n_in,
                              void* d_out, int out_size, void* d_ws, size_t ws_size,
                              hipStream_t stream) {
    const float* cnn  = (const float*)d_in[0];
    const float* vit  = (const float*)d_in[1];
    const float* Wq   = (const float*)d_in[2];
    const float* bq   = (const float*)d_in[3];
    const float* Wk   = (const float*)d_in[4];
    const float* bk   = (const float*)d_in[5];
    const float* Wv   = (const float*)d_in[6];
    const float* bv   = (const float*)d_in[7];
    const float* gam  = (const float*)d_in[8];
    const float* gcnn = (const float*)d_in[9];
    const float* gvit = (const float*)d_in[10];
    float* out = (float*)d_out;

    float* ws = (float*)d_ws;
    float*  part = ws;                           // 1,048,576 f (4 MB)
    float*  G    = ws + 1048576;                 // 32,768 f
    ushort* qb   = (ushort*)(ws + 1081344);      // 131,072 bf16
    ushort* kb   = (ushort*)(ws + 1146880);      // 131,072 bf16
    ushort* vF   = (ushort*)(ws + 1212416);      // 1,048,576 bf16 (frag layout)

    gram_k<<<256, 256, 0, stream>>>(cnn, vit, part);
    gred_k<<<512, 64,  0, stream>>>(part, G);
    qkvw_k<<<256, 256, 0, stream>>>(cnn, vit, G, Wq, Wk, Wv, gcnn, gvit,
                                    bq, bk, bv, qb, kb, vF);
    flashB<<<256, 512, 0, stream>>>(qb, kb, vF, cnn, gam, out);
}

// Round 6
// 121.484 us; speedup vs baseline: 1.7788x; 1.0005x over previous
//
#include <hip/hip_runtime.h>
#include <hip/hip_bf16.h>

#define BSZ 4
#define CC 64
#define NN 4096
#define CN (CC*NN)        // 262144
#define BCN (BSZ*CN)      // 1048576

typedef __attribute__((ext_vector_type(4))) float    f4v;
typedef __attribute__((ext_vector_type(4))) int      i4v;
typedef __attribute__((ext_vector_type(2))) int      i2v;
typedef __attribute__((ext_vector_type(8))) short    s8v;

__device__ __forceinline__ unsigned pack_bf16(float lo, float hi) {
    unsigned l = __builtin_bit_cast(unsigned, lo);
    unsigned h = __builtin_bit_cast(unsigned, hi);
    return (h & 0xFFFF0000u) | (l >> 16);
}
// single v_cvt_pk_bf16_f32 (RNE)
__device__ __forceinline__ unsigned pack2(float lo, float hi) {
    float2 f2; f2.x = lo; f2.y = hi;
    __hip_bfloat162 h = __float22bfloat162_rn(f2);
    unsigned u;
    __builtin_memcpy(&u, &h, 4);
    return u;
}

// ---------------------------------------------------------------------------
// K1 (R6): gram partials, 64-wide n-chunks. grid 512 = (i2:2, b:4, ch:64).
// 17 KB LDS -> 2 blocks/CU (2 waves/SIMD) so the VALU k-loop has a partner
// wave to hide global/LDS latency (R5 ran 1 wave/SIMD). Coalesced flat
// output store via LDS restage (pitch 65).
__global__ __launch_bounds__(256) void gram_k(const float* __restrict__ cnn,
                                              const float* __restrict__ vit,
                                              float* __restrict__ part) {
    __shared__ __align__(16) float sXT[64*68];        // [n][c], pitch 68
    int t = threadIdx.x;
    int blk = blockIdx.x;
    int ch = blk & 63, b = (blk >> 6) & 3, i2 = blk >> 8;
    const float* X = (i2 ? vit : cnn) + b * CN;
    int n0 = ch * 64;
#pragma unroll
    for (int j = 0; j < 4; j++) {
        int idx = t + j * 256;                        // 0..1023
        int c = idx >> 4, n4 = idx & 15;
        f4v val = *(const f4v*)&X[c * NN + n0 + n4 * 4];
        int base = (n4 * 4) * 68 + c;
        sXT[base]       = val[0];
        sXT[base + 68]  = val[1];
        sXT[base + 136] = val[2];
        sXT[base + 204] = val[3];
    }
    __syncthreads();
    int tc = (t & 15) * 4, td = (t >> 4) * 4;
    f4v acc[4];
#pragma unroll
    for (int i = 0; i < 4; i++) acc[i] = (f4v){0.f, 0.f, 0.f, 0.f};
#pragma unroll 4
    for (int k = 0; k < 64; k++) {
        f4v a  = *(const f4v*)&sXT[k * 68 + tc];
        f4v bb = *(const f4v*)&sXT[k * 68 + td];
#pragma unroll
        for (int i = 0; i < 4; i++) acc[i] += a[i] * bb;
    }
    __syncthreads();                                  // sXT reads done
    float* sOut = sXT;                                // reuse, pitch 65
#pragma unroll
    for (int i = 0; i < 4; i++)
        *(f4v*)&sOut[(tc + i) * 65 + td] = acc[i];
    __syncthreads();
    float* dst = part + (size_t)((i2 * 4 + b) * 64 + ch) * 4096;
#pragma unroll
    for (int j = 0; j < 4; j++) {
        int flat = j * 1024 + t * 4;                  // r*64 + d
        int r = flat >> 6, d = flat & 63;
        *(f4v*)&dst[flat] = *(const f4v*)&sOut[r * 65 + d];
    }
}

// ---------------------------------------------------------------------------
// K2 (R6): reduce 64 gram partials + fused channel softmax, f4-vectorized.
__global__ void gred_k(const float* __restrict__ part, float* __restrict__ G) {
    int R = blockIdx.x;                               // 512 = 2*B*C rows
    int t = threadIdx.x;                              // 64
    int i2b = R >> 6, r = R & 63;
    int l16 = t & 15, grp = t >> 4;
    const float* base = part + (size_t)i2b * 64 * 4096 + r * 64 + l16 * 4;
    f4v s = (f4v){0.f, 0.f, 0.f, 0.f};
#pragma unroll
    for (int c8 = 0; c8 < 16; c8++)
        s += *(const f4v*)(base + (size_t)(c8 * 4 + grp) * 4096);
    // reduce over ch-groups (xor 16, 32): all lanes now hold full sums
#pragma unroll
    for (int off = 16; off < 64; off <<= 1) {
        s[0] += __shfl_xor(s[0], off);
        s[1] += __shfl_xor(s[1], off);
        s[2] += __shfl_xor(s[2], off);
        s[3] += __shfl_xor(s[3], off);
    }
    float mn = fminf(fminf(s[0], s[1]), fminf(s[2], s[3]));
#pragma unroll
    for (int off = 1; off < 16; off <<= 1) mn = fminf(mn, __shfl_xor(mn, off));
    f4v e;
    float sm = 0.f;
#pragma unroll
    for (int j = 0; j < 4; j++) { e[j] = __expf(mn - s[j]); sm += e[j]; }
#pragma unroll
    for (int off = 1; off < 16; off <<= 1) sm += __shfl_xor(sm, off);
    if (t < 16) {
        f4v o;
#pragma unroll
        for (int j = 0; j < 4; j++) o[j] = e[j] / sm;
        *(f4v*)&G[(size_t)R * 64 + l16 * 4] = o;
    }
}

// ---------------------------------------------------------------------------
// K3: weff fused into qkv (unchanged from R5). Each block recomputes its b's
// 80x64 Weff (= g*(W·A)+W) from G; sWt pitch-65; then MFMA QKV body; V
// emitted directly in flash PV A-frag layout.
__global__ __launch_bounds__(256) void qkvw_k(const float* __restrict__ cnn,
                                              const float* __restrict__ vit,
                                              const float* __restrict__ G,
                                              const float* __restrict__ Wq,
                                              const float* __restrict__ Wk,
                                              const float* __restrict__ Wv,
                                              const float* __restrict__ gcnn,
                                              const float* __restrict__ gvit,
                                              const float* __restrict__ bq,
                                              const float* __restrict__ bk,
                                              const float* __restrict__ bv,
                                              ushort* __restrict__ qb,
                                              ushort* __restrict__ kb,
                                              ushort* __restrict__ vF) {
    __shared__ __align__(16) float sA[8192];          // Gc | Gv ; later vbuf
    __shared__ float sWt[5200];                       // 5 tiles, pitch 65
    int t = threadIdx.x;
    int b = blockIdx.x >> 6, ktg = blockIdx.x & 63, n0 = ktg * 64;
    int w = t >> 6, lane = t & 63, c15 = lane & 15, q4 = lane >> 4;
    int n = n0 + w * 16 + c15;
    const float LOG2E = 1.44269504f;

#pragma unroll
    for (int i = 0; i < 4; i++) {
        int idx = (i * 256 + t) * 4;
        *(f4v*)&sA[idx]        = *(const f4v*)&G[(size_t)b * 4096 + idx];
        *(f4v*)&sA[4096 + idx] = *(const f4v*)&G[(size_t)(4 + b) * 4096 + idx];
    }
    __syncthreads();

    {
        int r16 = w, c = t & 63;
        float gc = *gcnn, gv = *gvit;
        float acc[4][5];
#pragma unroll
        for (int mi = 0; mi < 4; mi++)
#pragma unroll
            for (int tl = 0; tl < 5; tl++) acc[mi][tl] = 0.f;
#pragma unroll 4
        for (int d = 0; d < 64; d++) {
            float av = sA[4096 + d * 64 + c];
            float ac = sA[d * 64 + c];
#pragma unroll
            for (int mi = 0; mi < 4; mi++) {
                int m = mi * 4 + r16;
                if (mi < 2)
                    acc[mi][0] += Wq[m * 64 + d] * ac;
                else
                    acc[mi][0] += Wk[(m - 8) * 64 + d] * av;
#pragma unroll
                for (int tl = 1; tl < 5; tl++)
                    acc[mi][tl] += Wv[((tl - 1) * 16 + m) * 64 + d] * av;
            }
        }
#pragma unroll
        for (int mi = 0; mi < 4; mi++) {
            int m = mi * 4 + r16;
            if (mi < 2)
                sWt[m * 65 + c] = gc * acc[mi][0] + Wq[m * 64 + c];
            else
                sWt[m * 65 + c] = gv * acc[mi][0] + Wk[(m - 8) * 64 + c];
#pragma unroll
            for (int tl = 1; tl < 5; tl++)
                sWt[tl * 1040 + m * 65 + c] =
                    gv * acc[mi][tl] + Wv[((tl - 1) * 16 + m) * 64 + c];
        }
    }
    __syncthreads();

    s8v A[10];
#pragma unroll
    for (int i = 0; i < 10; i++) {
        int tile = i >> 1, frag = i & 1;
        const float* src = &sWt[tile * 1040 + (lane & 15) * 65 + frag * 32 + q4 * 8];
        i4v o;
#pragma unroll
        for (int p = 0; p < 4; p++)
            o[p] = (int)pack_bf16(src[2 * p], src[2 * p + 1]);
        A[i] = __builtin_bit_cast(s8v, o);
    }

    s8v Bc[2], Bv[2];
#pragma unroll
    for (int f = 0; f < 2; f++) {
        i4v pc, pv;
#pragma unroll
        for (int p = 0; p < 4; p++) {
            int c0 = f * 32 + q4 * 8 + p * 2;
            size_t a0 = (size_t)b * CN + (size_t)c0 * NN + n;
            pc[p] = (int)pack_bf16(cnn[a0], cnn[a0 + NN]);
            pv[p] = (int)pack_bf16(vit[a0], vit[a0 + NN]);
        }
        Bc[f] = __builtin_bit_cast(s8v, pc);
        Bv[f] = __builtin_bit_cast(s8v, pv);
    }

    f4v acc = *(const f4v*)(bq + (q4 & 1) * 4);
    acc = __builtin_amdgcn_mfma_f32_16x16x32_bf16(A[0], Bc[0], acc, 0, 0, 0);
    acc = __builtin_amdgcn_mfma_f32_16x16x32_bf16(A[1], Bc[1], acc, 0, 0, 0);
    if (q4 < 2) {
        unsigned d0 = pack_bf16(acc[0] * LOG2E, acc[1] * LOG2E);
        unsigned d1 = pack_bf16(acc[2] * LOG2E, acc[3] * LOG2E);
        unsigned long long v = ((unsigned long long)d1 << 32) | d0;
        *(unsigned long long*)&qb[(size_t)(b * NN + n) * 8 + q4 * 4] = v;
    }
    acc = *(const f4v*)(bk + (q4 & 1) * 4);
    acc = __builtin_amdgcn_mfma_f32_16x16x32_bf16(A[0], Bv[0], acc, 0, 0, 0);
    acc = __builtin_amdgcn_mfma_f32_16x16x32_bf16(A[1], Bv[1], acc, 0, 0, 0);
    if (q4 >= 2) {
        unsigned d0 = pack_bf16(acc[0], acc[1]), d1 = pack_bf16(acc[2], acc[3]);
        unsigned long long v = ((unsigned long long)d1 << 32) | d0;
        *(unsigned long long*)&kb[(size_t)(b * NN + n) * 8 + (q4 - 2) * 4] = v;
    }
    float* vbuf = sA;
#pragma unroll
    for (int tile = 1; tile < 5; tile++) {
        acc = *(const f4v*)(bv + (tile - 1) * 16 + q4 * 4);
        acc = __builtin_amdgcn_mfma_f32_16x16x32_bf16(A[tile * 2],     Bv[0], acc, 0, 0, 0);
        acc = __builtin_amdgcn_mfma_f32_16x16x32_bf16(A[tile * 2 + 1], Bv[1], acc, 0, 0, 0);
#pragma unroll
        for (int r = 0; r < 4; r++)
            vbuf[((tile - 1) * 16 + q4 * 4 + r) * 67 + w * 16 + c15] = acc[r];
    }
    __syncthreads();
    {
        int nt = w;
#pragma unroll
        for (int F = 0; F < 2; F++) {
            float vv[8];
#pragma unroll
            for (int e = 0; e < 8; e++)
                vv[e] = vbuf[(nt * 16 + c15) * 67 + 32 * F + 16 * (e >> 2)
                             + 4 * q4 + (e & 3)];
            i4v o;
#pragma unroll
            for (int p = 0; p < 4; p++)
                o[p] = (int)pack_bf16(vv[2 * p], vv[2 * p + 1]);
            *(i4v*)&vF[((size_t)((b * 64 + ktg) * 8 + nt * 2 + F)) * 512 + lane * 8] = o;
        }
    }
}

// ---------------------------------------------------------------------------
// K4 (R6): barrier-free flash, 512 threads / 8 waves. L computed by ONES-ROW
// MFMA (accL += ones^T · P): removes the per-kt 16-add serial VALU sum and
// the end-of-loop cross-lane shuffles; L is the sum of the SAME bf16-rounded
// P the PV numerator uses (self-consistent softmax). grid 256 = (b:4, qc:64).
__global__ __launch_bounds__(512, 2) void flashB(
        const ushort* __restrict__ qb, const ushort* __restrict__ kb,
        const ushort* __restrict__ vF, const float* __restrict__ cnn,
        const float* __restrict__ gamma, float* __restrict__ out) {
    __shared__ __align__(16) float sO[4][64 * 68];    // 4 x 17KB slabs
    __shared__ float sL[8][64];
    __shared__ __align__(16) float sRv[64];

    int t = threadIdx.x;
    int lane = t & 63, w = t >> 6;                    // wave 0..7
    int c15 = lane & 15, q4 = lane >> 4;
    int blk = blockIdx.x;
    int b = blk >> 6, q0 = (blk & 63) * 64;
    float gm = *gamma;

    s8v qB[4];
#pragma unroll
    for (int g = 0; g < 4; g++) {
        i4v qa = (i4v){0, 0, 0, 0};
        if (q4 == 0)
            qa = *(const i4v*)(qb + (size_t)(b * NN + q0 + g * 16 + c15) * 8);
        qB[g] = __builtin_bit_cast(s8v, qa);
    }

    // all-ones bf16 A-fragment for the L row-sum MFMA
    i4v onesi;
#pragma unroll
    for (int p = 0; p < 4; p++) onesi[p] = 0x3F803F80;
    s8v onesA = __builtin_bit_cast(s8v, onesi);

    f4v accO[4][4];
    f4v accL[4];
#pragma unroll
    for (int g = 0; g < 4; g++) {
        accL[g] = (f4v){0.f, 0.f, 0.f, 0.f};
#pragma unroll
        for (int nt = 0; nt < 4; nt++) accO[g][nt] = (f4v){0.f, 0.f, 0.f, 0.f};
    }

    const ushort* kbb = kb + (size_t)b * NN * 8 + (size_t)c15 * 8;
    const ushort* vfb = vF + (size_t)b * 64 * 8 * 512 + (size_t)lane * 8;
    int kq = w * 512;                                 // wave's k-base

    i4v bkc[4];
#pragma unroll
    for (int nt = 0; nt < 4; nt++)
        bkc[nt] = *(const i4v*)(kbb + (size_t)(kq + nt * 16) * 8);

    for (int kt = 0; kt < 8; kt++) {
        int ktg = (kq >> 6) + kt;
        i4v vA[2][4];
#pragma unroll
        for (int F = 0; F < 2; F++)
#pragma unroll
            for (int nt = 0; nt < 4; nt++)
                vA[F][nt] = *(const i4v*)(vfb +
                    (size_t)(ktg * 8 + nt * 2 + F) * 512);
        i4v bkn[4];
        if (kt < 7) {
#pragma unroll
            for (int nt = 0; nt < 4; nt++)
                bkn[nt] = *(const i4v*)(kbb +
                    (size_t)(kq + (kt + 1) * 64 + nt * 16) * 8);
        }

#pragma unroll
        for (int g = 0; g < 4; g++) {
            f4v z = (f4v){0.f, 0.f, 0.f, 0.f};
            f4v S[4];
#pragma unroll
            for (int nt = 0; nt < 4; nt++)
                S[nt] = __builtin_amdgcn_mfma_f32_16x16x32_bf16(
                    __builtin_bit_cast(s8v, bkc[nt]), qB[g], z, 0, 0, 0);
            f4v p[4];
#pragma unroll
            for (int nt = 0; nt < 4; nt++)
#pragma unroll
                for (int rr = 0; rr < 4; rr++)
                    p[nt][rr] = __builtin_amdgcn_exp2f(S[nt][rr]);
            s8v Bp[2];
#pragma unroll
            for (int F = 0; F < 2; F++) {
                i4v bp;
                bp[0] = (int)pack2(p[2 * F][0],     p[2 * F][1]);
                bp[1] = (int)pack2(p[2 * F][2],     p[2 * F][3]);
                bp[2] = (int)pack2(p[2 * F + 1][0], p[2 * F + 1][1]);
                bp[3] = (int)pack2(p[2 * F + 1][2], p[2 * F + 1][3]);
                Bp[F] = __builtin_bit_cast(s8v, bp);
            }
            __builtin_amdgcn_s_setprio(1);
            accL[g] = __builtin_amdgcn_mfma_f32_16x16x32_bf16(
                onesA, Bp[0], accL[g], 0, 0, 0);
            accL[g] = __builtin_amdgcn_mfma_f32_16x16x32_bf16(
                onesA, Bp[1], accL[g], 0, 0, 0);
#pragma unroll
            for (int F = 0; F < 2; F++)
#pragma unroll
                for (int nt = 0; nt < 4; nt++)
                    accO[g][nt] = __builtin_amdgcn_mfma_f32_16x16x32_bf16(
                        __builtin_bit_cast(s8v, vA[F][nt]), Bp[F],
                        accO[g][nt], 0, 0, 0);
            __builtin_amdgcn_s_setprio(0);
        }
        if (kt < 7) {
#pragma unroll
            for (int nt = 0; nt < 4; nt++) bkc[nt] = bkn[nt];
        }
    }

    // per-wave L partials: every accL row holds sum_k P[k][q]; lane col = q
    if (q4 == 0) {
#pragma unroll
        for (int g = 0; g < 4; g++) sL[w][g * 16 + c15] = accL[g][0];
    }

    // 8->1 combine tree
    auto WRS = [&](float* s) {
#pragma unroll
        for (int g = 0; g < 4; g++)
#pragma unroll
            for (int nt = 0; nt < 4; nt++)
#pragma unroll
                for (int rr = 0; rr < 4; rr++)
                    s[(nt * 16 + q4 * 4 + rr) * 68 + g * 16 + c15] = accO[g][nt][rr];
    };
    auto ADS = [&](const float* s) {
#pragma unroll
        for (int g = 0; g < 4; g++)
#pragma unroll
            for (int nt = 0; nt < 4; nt++)
#pragma unroll
                for (int rr = 0; rr < 4; rr++)
                    accO[g][nt][rr] += s[(nt * 16 + q4 * 4 + rr) * 68 + g * 16 + c15];
    };

    if (w >= 4) WRS(sO[w - 4]);
    __syncthreads();                                  // #1
    if (w < 4)  ADS(sO[w]);
    if (w == 2 || w == 3) WRS(sO[w]);                 // own slab (already read)
    if (w == 4) {                                     // rv = gamma / L
        float Ls = 0.f;
#pragma unroll
        for (int i = 0; i < 8; i++) Ls += sL[i][lane];
        sRv[lane] = gm / Ls;
    }
    __syncthreads();                                  // #2
    if (w == 0) ADS(sO[2]);
    if (w == 1) { ADS(sO[3]); WRS(sO[1]); }
    __syncthreads();                                  // #3
    if (w == 0) { ADS(sO[1]); WRS(sO[0]); }
    __syncthreads();                                  // #4

    // epilogue: out = O*rv + cnn (512 threads, coalesced)
    {
        int c = t >> 3, qo = (t & 7) * 8;
        f4v o0 = *(const f4v*)&sO[0][c * 68 + qo];
        f4v o1 = *(const f4v*)&sO[0][c * 68 + qo + 4];
        f4v r0 = *(const f4v*)&sRv[qo];
        f4v r1 = *(const f4v*)&sRv[qo + 4];
        size_t gi = (size_t)(b * 64 + c) * NN + q0 + qo;
        f4v c0 = *(const f4v*)&cnn[gi];
        f4v c1 = *(const f4v*)&cnn[gi + 4];
        *(f4v*)&out[gi]     = o0 * r0 + c0;
        *(f4v*)&out[gi + 4] = o1 * r1 + c1;
    }
}

// ---------------------------------------------------------------------------
extern "C" void kernel_launch(void* const* d_in, const int* in_sizes, int n_in,
                              void* d_out, int out_size, void* d_ws, size_t ws_size,
                              hipStream_t stream) {
    const float* cnn  = (const float*)d_in[0];
    const float* vit  = (const float*)d_in[1];
    const float* Wq   = (const float*)d_in[2];
    const float* bq   = (const float*)d_in[3];
    const float* Wk   = (const float*)d_in[4];
    const float* bk   = (const float*)d_in[5];
    const float* Wv   = (const float*)d_in[6];
    const float* bv   = (const float*)d_in[7];
    const float* gam  = (const float*)d_in[8];
    const float* gcnn = (const float*)d_in[9];
    const float* gvit = (const float*)d_in[10];
    float* out = (float*)d_out;

    float* ws = (float*)d_ws;
    float*  part = ws;                           // 2,097,152 f (8 MB)
    float*  G    = ws + 2097152;                 // 32,768 f
    ushort* qb   = (ushort*)(ws + 2129920);      // 131,072 bf16
    ushort* kb   = (ushort*)(ws + 2195456);      // 131,072 bf16
    ushort* vF   = (ushort*)(ws + 2260992);      // 1,048,576 bf16 (frag layout)

    gram_k<<<512, 256, 0, stream>>>(cnn, vit, part);
    gred_k<<<512, 64,  0, stream>>>(part, G);
    qkvw_k<<<256, 256, 0, stream>>>(cnn, vit, G, Wq, Wk, Wv, gcnn, gvit,
                                    bq, bk, bv, qb, kb, vF);
    flashB<<<256, 512, 0, stream>>>(qb, kb, vF, cnn, gam, out);
}